// Round 10
// baseline (198.629 us; speedup 1.0000x reference)
//
#include <hip/hip_runtime.h>
#include <math.h>
#include <stdint.h>

#define DMODEL 1024
#define DINNER 2048
#define DCONV  4
#define DSTATE 16
#define DTRANK 64
#define BB 2
#define LL 1024
#define MM (BB * LL)            // 2048 rows in all GEMMs

#define CL  64                  // scan chunk length
#define NCH (LL / CL)           // 16 chunks

#define AS1(p) ((__attribute__((address_space(1))) void*)(void*)(p))
#define AS3(p) ((__attribute__((address_space(3))) void*)(void*)(p))

typedef __attribute__((ext_vector_type(8))) short bf16x8;
typedef __attribute__((ext_vector_type(4))) float f32x4;

__device__ __forceinline__ ushort bf16_rne(float f) {
  uint32_t u = __float_as_uint(f);
  uint32_t r = (u + 0x7fffu + ((u >> 16) & 1u)) >> 16;
  return (ushort)r;
}

// ---------------------------------------------------------------------------
// Fused f32 -> (hi[, lo]) bf16 split for 4 arrays in one launch.
// ---------------------------------------------------------------------------
__device__ __forceinline__ void split4(const float* __restrict__ in,
                                       ushort* __restrict__ hi,
                                       ushort* __restrict__ lo, int i4) {
  const float4 v = *reinterpret_cast<const float4*>(in + (size_t)i4 * 4);
  ushort4 h;
  h.x = bf16_rne(v.x); h.y = bf16_rne(v.y);
  h.z = bf16_rne(v.z); h.w = bf16_rne(v.w);
  *reinterpret_cast<ushort4*>(hi + (size_t)i4 * 4) = h;
  if (lo) {
    ushort4 l;
    l.x = bf16_rne(v.x - __uint_as_float((uint)h.x << 16));
    l.y = bf16_rne(v.y - __uint_as_float((uint)h.y << 16));
    l.z = bf16_rne(v.z - __uint_as_float((uint)h.z << 16));
    l.w = bf16_rne(v.w - __uint_as_float((uint)h.w << 16));
    *reinterpret_cast<ushort4*>(lo + (size_t)i4 * 4) = l;
  }
}

__global__ __launch_bounds__(256)
void split3(const float* s0, ushort* h0, ushort* l0, int n0,
            const float* s1, ushort* h1, ushort* l1, int n1,
            const float* s2, ushort* h2, ushort* l2, int n2,
            const float* s3, ushort* h3, ushort* l3, int n3) {
  int i = blockIdx.x * 256 + threadIdx.x;
  if (i < n0) { split4(s0, h0, l0, i); return; }
  i -= n0;
  if (i < n1) { split4(s1, h1, l1, i); return; }
  i -= n1;
  if (i < n2) { split4(s2, h2, l2, i); return; }
  i -= n2;
  if (i < n3) { split4(s3, h3, l3, i); return; }
}

__device__ __forceinline__ int swz4(int r) { return (r & 3) ^ ((r >> 2) & 3); }

// ---------------------------------------------------------------------------
// Unified MFMA NT GEMM, A-direct (A fragments global->reg, B planes via LDS).
// NB  = B planes (1: bf16, 2: hi+lo split).  ALO = also use A-lo plane
// (3-product, dt_proj).  EPI 0: plain; 1: softplus(acc+bias); 2: silu for
// cn >= DINNER (in_proj z-gate).  SPLITK via blockIdx.z.
// 128x128 tile, BK=32, 4 waves, 2-phase double-buffered LDS for B only.
// ---------------------------------------------------------------------------
template<int NB, bool ALO, int EPI, int SPLITK>
__global__ __launch_bounds__(256)
void gemm_adirect(const ushort* __restrict__ Ag, const ushort* __restrict__ Alg,
                  const ushort* __restrict__ Bhg, const ushort* __restrict__ Blg,
                  float* __restrict__ C, const float* __restrict__ bias,
                  int M, int N, int K) {
  __shared__ ushort Bst[NB * 2][128][32];   // [plane*2 + buf][row][k]

  const int tid  = threadIdx.x;
  const int wave = tid >> 6;
  const int lane = tid & 63;
  const int m0 = blockIdx.y * 128;
  const int n0 = blockIdx.x * 128;
  const int wm = (wave >> 1) * 64;
  const int wn = (wave & 1) * 64;

  const int ksl = K / SPLITK;
  const int kb  = blockIdx.z * ksl;
  float* Cout   = C + (size_t)blockIdx.z * M * N;

  f32x4 acc[4][4];
  #pragma unroll
  for (int i = 0; i < 4; ++i)
    #pragma unroll
    for (int j = 0; j < 4; ++j)
      acc[i][j] = (f32x4){0.f, 0.f, 0.f, 0.f};

  const int lr = lane >> 2;   // row within 16-row segment (staging)
  const int ls = lane & 3;    // 16B slot (staging)
  const int fr = lane & 15;   // fragment row/col
  const int q  = lane >> 4;   // k-slot

  // stage NB planes of the 128x32 B tile into buffer bi (NB*2 loads/wave)
  auto STAGE = [&](int bi, int k0) {
    #pragma unroll
    for (int j = 0; j < NB * 2; ++j) {
      const int g   = wave * NB * 2 + j;   // 0..NB*8-1
      const int p   = g >> 3;              // plane
      const int seg = g & 7;
      const ushort* src = p ? Blg : Bhg;
      const int rho = seg * 16 + lr;
      const int ks  = (ls ^ swz4(rho)) * 8;
      __builtin_amdgcn_global_load_lds(
          AS1(src + (size_t)(n0 + rho) * K + k0 + ks),
          AS3(&Bst[p * 2 + bi][0][0] + seg * 512), 16, 0, 0);
    }
  };

  // direct global->reg A fragments for K-tile kt
  auto LOADA = [&](bf16x8* dh, bf16x8* dl, int kt) {
    #pragma unroll
    for (int f = 0; f < 4; ++f) {
      const size_t off = (size_t)(m0 + wm + f * 16 + fr) * K + kb + kt * 32 + q * 8;
      dh[f] = *reinterpret_cast<const bf16x8*>(Ag + off);
      if constexpr (ALO)
        dl[f] = *reinterpret_cast<const bf16x8*>(Alg + off);
    }
  };

  const int NT = ksl / 32;
  bf16x8 ahc[4], alc[4], ahn[4], aln[4];
  STAGE(0, kb);
  LOADA(ahc, alc, 0);
  __syncthreads();

  int cur = 0;
  for (int kt = 0; kt < NT; ++kt) {
    if (kt + 1 < NT) {
      STAGE(cur ^ 1, kb + (kt + 1) * 32);
      LOADA(ahn, aln, kt + 1);
    }

    bf16x8 bh[4], bl[4];
    #pragma unroll
    for (int f = 0; f < 4; ++f) {
      const int r = wn + f * 16 + fr;
      const int s = 8 * (q ^ swz4(r));
      bh[f] = *reinterpret_cast<const bf16x8*>(&Bst[cur][r][s]);
      if (NB == 2)
        bl[f] = *reinterpret_cast<const bf16x8*>(&Bst[2 + cur][r][s]);
    }
    #pragma unroll
    for (int i = 0; i < 4; ++i)
      #pragma unroll
      for (int j = 0; j < 4; ++j) {
        acc[i][j] = __builtin_amdgcn_mfma_f32_16x16x32_bf16(ahc[i], bh[j], acc[i][j], 0, 0, 0);
        if (NB == 2)
          acc[i][j] = __builtin_amdgcn_mfma_f32_16x16x32_bf16(ahc[i], bl[j], acc[i][j], 0, 0, 0);
        if constexpr (ALO)
          acc[i][j] = __builtin_amdgcn_mfma_f32_16x16x32_bf16(alc[i], bh[j], acc[i][j], 0, 0, 0);
      }

    __syncthreads();
    #pragma unroll
    for (int f = 0; f < 4; ++f) {
      ahc[f] = ahn[f];
      if constexpr (ALO) alc[f] = aln[f];
    }
    cur ^= 1;
  }

  const int cr = (lane >> 4) * 4;
  const int cc = lane & 15;
  #pragma unroll
  for (int i = 0; i < 4; ++i)
    #pragma unroll
    for (int j = 0; j < 4; ++j) {
      const int cn = n0 + wn + j * 16 + cc;
      const float bj = (EPI == 1) ? bias[cn] : 0.f;
      const size_t base = (size_t)(m0 + wm + i * 16 + cr) * N + cn;
      #pragma unroll
      for (int r = 0; r < 4; ++r) {
        float v = acc[i][j][r];
        if (EPI == 1) {
          v += bj;
          v = fmaxf(v, 0.f) + __logf(1.f + __expf(-fabsf(v)));   // softplus
        }
        if (EPI == 2 && cn >= DINNER)
          v = v / (1.f + __expf(-v));     // silu: z-gate precompute
        Cout[base + (size_t)r * N] = v;
      }
    }
}

// sum 4 split-K partial planes -> out
__global__ __launch_bounds__(256)
void splitk_reduce4(const float* __restrict__ P, float* __restrict__ out, int n) {
  const int i = (blockIdx.x * 256 + threadIdx.x) * 4;
  if (i >= n) return;
  float4 s = *reinterpret_cast<const float4*>(P + i);
  #pragma unroll
  for (int z = 1; z < 4; ++z) {
    const float4 v = *reinterpret_cast<const float4*>(P + (size_t)z * n + i);
    s.x += v.x; s.y += v.y; s.z += v.z; s.w += v.w;
  }
  *reinterpret_cast<float4*>(out + i) = s;
}

// ---------------------------------------------------------------------------
// Split-K f32 NT GEMM partials (x_proj)
// ---------------------------------------------------------------------------
template<int BM, int BN, int TM, int TN, int KSLICE>
__global__ __launch_bounds__(256)
void gemm_nt_part(const float* __restrict__ A, const float* __restrict__ Bw,
                  float* __restrict__ P, int M, int N, int lda, int ldb) {
  constexpr int BK  = 16;
  constexpr int NTX = BN / TN;
  constexpr int NTY = BM / TM;
  static_assert(NTX * NTY == 256, "thread tile mismatch");
  __shared__ float As[BK][BM + 4];
  __shared__ float Bs[BK][BN + 4];

  const int tid = threadIdx.x;
  const int m0  = blockIdx.y * BM;
  const int n0  = blockIdx.x * BN;
  const int kb  = blockIdx.z * KSLICE;
  const int tx  = tid % NTX;
  const int ty  = tid / NTX;

  float acc[TM][TN] = {};

  for (int k0 = kb; k0 < kb + KSLICE; k0 += BK) {
    __syncthreads();
    for (int t = tid; t < BM * 4; t += 256) {
      const int row = t >> 2, kq = t & 3;
      const float4 v = *reinterpret_cast<const float4*>(
          A + (size_t)(m0 + row) * lda + k0 + kq * 4);
      As[kq * 4 + 0][row] = v.x;
      As[kq * 4 + 1][row] = v.y;
      As[kq * 4 + 2][row] = v.z;
      As[kq * 4 + 3][row] = v.w;
    }
    for (int t = tid; t < BN * 4; t += 256) {
      const int row = t >> 2, kq = t & 3;
      const float4 v = *reinterpret_cast<const float4*>(
          Bw + (size_t)(n0 + row) * ldb + k0 + kq * 4);
      Bs[kq * 4 + 0][row] = v.x;
      Bs[kq * 4 + 1][row] = v.y;
      Bs[kq * 4 + 2][row] = v.z;
      Bs[kq * 4 + 3][row] = v.w;
    }
    __syncthreads();
    #pragma unroll
    for (int k = 0; k < BK; ++k) {
      float a[TM], b[TN];
      #pragma unroll
      for (int i = 0; i < TM; ++i) a[i] = As[k][ty * TM + i];
      #pragma unroll
      for (int j = 0; j < TN; ++j) b[j] = Bs[k][tx * TN + j];
      #pragma unroll
      for (int i = 0; i < TM; ++i)
        #pragma unroll
        for (int j = 0; j < TN; ++j)
          acc[i][j] = fmaf(a[i], b[j], acc[i][j]);
    }
  }

  float* out = P + (size_t)blockIdx.z * M * N;
  #pragma unroll
  for (int i = 0; i < TM; ++i)
    #pragma unroll
    for (int j = 0; j < TN; ++j)
      out[(size_t)(m0 + ty * TM + i) * N + n0 + tx * TN + j] = acc[i][j];
}

// reduce x_proj partials; dt cols (0..63) -> packed bf16 hi/lo, B/C cols -> f32
__global__ __launch_bounds__(256)
void xpr_fused(const float* __restrict__ part, float* __restrict__ xdbl,
               ushort* __restrict__ dth, ushort* __restrict__ dtl) {
  const int i = blockIdx.x * 256 + threadIdx.x;   // float4 over [2048][24]
  if (i >= MM * 24) return;
  const int m  = i / 24;
  const int c4 = (i % 24) * 4;
  const size_t off = (size_t)m * 96 + c4;
  float4 s = *reinterpret_cast<const float4*>(part + off);
  #pragma unroll
  for (int z = 1; z < 8; ++z) {
    const float4 v = *reinterpret_cast<const float4*>(part + (size_t)z * MM * 96 + off);
    s.x += v.x; s.y += v.y; s.z += v.z; s.w += v.w;
  }
  if (c4 < 64) {
    ushort4 h, l;
    h.x = bf16_rne(s.x); l.x = bf16_rne(s.x - __uint_as_float((uint)h.x << 16));
    h.y = bf16_rne(s.y); l.y = bf16_rne(s.y - __uint_as_float((uint)h.y << 16));
    h.z = bf16_rne(s.z); l.z = bf16_rne(s.z - __uint_as_float((uint)h.z << 16));
    h.w = bf16_rne(s.w); l.w = bf16_rne(s.w - __uint_as_float((uint)h.w << 16));
    *reinterpret_cast<ushort4*>(dth + (size_t)m * 64 + c4) = h;
    *reinterpret_cast<ushort4*>(dtl + (size_t)m * 64 + c4) = l;
  } else {
    *reinterpret_cast<float4*>(xdbl + off) = s;
  }
}

// ---------------------------------------------------------------------------
// Depthwise causal conv1d (k=4) + bias + SiLU, float4-vectorized.
// ---------------------------------------------------------------------------
__global__ __launch_bounds__(256)
void conv_silu(const float* __restrict__ xz, const float* __restrict__ cw,
               const float* __restrict__ cb, float* __restrict__ xc) {
  const int idx = blockIdx.x * 256 + threadIdx.x;   // over MM*DINNER/4
  if (idx >= MM * DINNER / 4) return;
  const int d4 = (idx & 511) * 4;       // DINNER/4 = 512 per row
  const int m  = idx >> 9;
  const int l  = m & (LL - 1);
  const int b  = m >> 10;

  float4 w0 = *reinterpret_cast<const float4*>(cw + (size_t)(d4 + 0) * 4);
  float4 w1 = *reinterpret_cast<const float4*>(cw + (size_t)(d4 + 1) * 4);
  float4 w2 = *reinterpret_cast<const float4*>(cw + (size_t)(d4 + 2) * 4);
  float4 w3 = *reinterpret_cast<const float4*>(cw + (size_t)(d4 + 3) * 4);
  float4 acc = *reinterpret_cast<const float4*>(cb + d4);

  #pragma unroll
  for (int j = 0; j < DCONV; ++j) {
    const int ll = l - (DCONV - 1) + j;
    if (ll >= 0) {
      const float4 xv = *reinterpret_cast<const float4*>(
          xz + ((size_t)(b * LL + ll) << 12) + d4);
      acc.x = fmaf(xv.x, (&w0.x)[j], acc.x);
      acc.y = fmaf(xv.y, (&w1.x)[j], acc.y);
      acc.z = fmaf(xv.z, (&w2.x)[j], acc.z);
      acc.w = fmaf(xv.w, (&w3.x)[j], acc.w);
    }
  }
  float4 o;
  o.x = acc.x / (1.f + __expf(-acc.x));
  o.y = acc.y / (1.f + __expf(-acc.y));
  o.z = acc.z / (1.f + __expf(-acc.z));
  o.w = acc.w / (1.f + __expf(-acc.w));
  *reinterpret_cast<float4*>(xc + (size_t)m * DINNER + d4) = o;
}

// ---------------------------------------------------------------------------
// Chunked parallel selective scan (3 passes).
// ---------------------------------------------------------------------------
__device__ __forceinline__ void stage_tile(const float* g, int stride,
                                           float* ldst, int lane) {
  const int r  = lane >> 2;
  const int q4 = (lane & 3) * 4;
  #pragma unroll
  for (int i = 0; i < 4; ++i) {
    __builtin_amdgcn_global_load_lds(
        AS1(g + (size_t)(i * 16 + r) * stride + q4),
        AS3(ldst + i * 256), 16, 0, 0);
  }
}

__device__ __forceinline__ float quad_sum(float v) {
  int i = __float_as_int(v);
  v += __int_as_float(__builtin_amdgcn_update_dpp(0, i, 0xB1, 0xf, 0xf, true)); // xor 1
  i = __float_as_int(v);
  v += __int_as_float(__builtin_amdgcn_update_dpp(0, i, 0x4E, 0xf, 0xf, true)); // xor 2
  return v;
}

__global__ __launch_bounds__(64)
void scan_chunk_state(const float* __restrict__ delta, const float* __restrict__ xc,
                      const float* __restrict__ xdbl, const float* __restrict__ A_log,
                      float* __restrict__ hend, float* __restrict__ aprod) {
  __shared__ float dT[CL][16];
  __shared__ float xT[CL][16];
  __shared__ float bT[CL][16];

  const int idx = blockIdx.x;          // (b*128 + dg)*16 + c
  const int c  = idx & 15;
  const int dg = (idx >> 4) & 127;
  const int b  = idx >> 11;
  const int t  = threadIdx.x;
  const int ch = t >> 2;
  const int q  = t & 3;
  const int d  = dg * 16 + ch;

  const size_t r0 = (size_t)b * LL + (size_t)c * CL;
  stage_tile(delta + r0 * DINNER + dg * 16, DINNER, &dT[0][0], t);
  stage_tile(xc    + r0 * DINNER + dg * 16, DINNER, &xT[0][0], t);
  stage_tile(xdbl  + r0 * 96 + DTRANK,          96, &bT[0][0], t);

  float Adn[4];
  #pragma unroll
  for (int j = 0; j < 4; ++j)
    Adn[j] = -__expf(A_log[d * DSTATE + 4 * q + j]);
  float h0 = 0.f, h1 = 0.f, h2 = 0.f, h3 = 0.f;
  float p0 = 1.f, p1 = 1.f, p2 = 1.f, p3 = 1.f;

  __syncthreads();

  #pragma unroll 8
  for (int l = 0; l < CL; ++l) {
    const float dv = dT[l][ch];
    const float xv = xT[l][ch];
    const float4 B4 = *reinterpret_cast<const float4*>(&bT[l][4 * q]);
    const float dvx = dv * xv;
    const float a0 = __expf(dv * Adn[0]);
    const float a1 = __expf(dv * Adn[1]);
    const float a2 = __expf(dv * Adn[2]);
    const float a3 = __expf(dv * Adn[3]);
    h0 = fmaf(a0, h0, dvx * B4.x);  p0 *= a0;
    h1 = fmaf(a1, h1, dvx * B4.y);  p1 *= a1;
    h2 = fmaf(a2, h2, dvx * B4.z);  p2 *= a2;
    h3 = fmaf(a3, h3, dvx * B4.w);  p3 *= a3;
  }

  const size_t base = (((size_t)(b * NCH + c) * DINNER) + d) * DSTATE + 4 * q;
  *reinterpret_cast<float4*>(hend  + base) = (float4){h0, h1, h2, h3};
  *reinterpret_cast<float4*>(aprod + base) = (float4){p0, p1, p2, p3};
}

__global__ __launch_bounds__(256)
void scan_combine(const float* __restrict__ hend, const float* __restrict__ aprod,
                  float* __restrict__ hin) {
  const int tid = blockIdx.x * 256 + threadIdx.x;   // 65536 total
  const size_t cstride = (size_t)DINNER * DSTATE;   // 32768
  const size_t base = (size_t)(tid >> 15) * NCH * cstride + (tid & 32767);
  float h = 0.f;
  hin[base] = 0.f;
  #pragma unroll
  for (int c = 0; c < NCH - 1; ++c) {
    h = fmaf(aprod[base + (size_t)c * cstride], h, hend[base + (size_t)c * cstride]);
    hin[base + (size_t)(c + 1) * cstride] = h;
  }
}

__global__ __launch_bounds__(64)
void scan_apply(const float* __restrict__ delta, const float* __restrict__ xc,
                const float* __restrict__ xdbl, const float* __restrict__ xz,
                const float* __restrict__ A_log, const float* __restrict__ Dp,
                const float* __restrict__ hin, ushort* __restrict__ yh) {
  __shared__ float dT[CL][16];
  __shared__ float xT[CL][16];
  __shared__ float bT[CL][16];
  __shared__ float cT[CL][16];
  __shared__ float zT[CL][16];

  const int idx = blockIdx.x;
  const int c  = idx & 15;
  const int dg = (idx >> 4) & 127;
  const int b  = idx >> 11;
  const int t  = threadIdx.x;
  const int ch = t >> 2;
  const int q  = t & 3;
  const int d  = dg * 16 + ch;

  const size_t r0 = (size_t)b * LL + (size_t)c * CL;
  stage_tile(delta + r0 * DINNER + dg * 16, DINNER, &dT[0][0], t);
  stage_tile(xc    + r0 * DINNER + dg * 16, DINNER, &xT[0][0], t);
  stage_tile(xdbl  + r0 * 96 + DTRANK,          96, &bT[0][0], t);
  stage_tile(xdbl  + r0 * 96 + DTRANK + DSTATE, 96, &cT[0][0], t);
  stage_tile(xz    + (r0 << 12) + DINNER + dg * 16, 4096, &zT[0][0], t);

  float Adn[4];
  #pragma unroll
  for (int j = 0; j < 4; ++j)
    Adn[j] = -__expf(A_log[d * DSTATE + 4 * q + j]);
  const float Dd = Dp[d];

  const size_t base = (((size_t)(b * NCH + c) * DINNER) + d) * DSTATE + 4 * q;
  const float4 h4 = *reinterpret_cast<const float4*>(hin + base);
  float h0 = h4.x, h1 = h4.y, h2 = h4.z, h3 = h4.w;

  __syncthreads();

  #pragma unroll 8
  for (int l = 0; l < CL; ++l) {
    const float dv = dT[l][ch];
    const float xv = xT[l][ch];
    const float4 B4 = *reinterpret_cast<const float4*>(&bT[l][4 * q]);
    const float4 C4 = *reinterpret_cast<const float4*>(&cT[l][4 * q]);
    const float dvx = dv * xv;
    const float a0 = __expf(dv * Adn[0]);
    const float a1 = __expf(dv * Adn[1]);
    const float a2 = __expf(dv * Adn[2]);
    const float a3 = __expf(dv * Adn[3]);
    h0 = fmaf(a0, h0, dvx * B4.x);
    h1 = fmaf(a1, h1, dvx * B4.y);
    h2 = fmaf(a2, h2, dvx * B4.z);
    h3 = fmaf(a3, h3, dvx * B4.w);
    float ys = fmaf(h0, C4.x, fmaf(h1, C4.y, fmaf(h2, C4.z, h3 * C4.w)));
    ys = quad_sum(ys);
    if (q == 0) {
      const float g = zT[l][ch];        // silu(z) precomputed by in_proj epilogue
      const float tv = (ys + xv * Dd) * g;
      yh[(r0 + l) * (size_t)DINNER + d] = bf16_rne(tv);
    }
  }
}

// ---------------------------------------------------------------------------
extern "C" void kernel_launch(void* const* d_in, const int* in_sizes, int n_in,
                              void* d_out, int out_size, void* d_ws, size_t ws_size,
                              hipStream_t stream) {
  const float* x         = (const float*)d_in[0];
  const float* in_proj_w = (const float*)d_in[1];
  const float* conv_w    = (const float*)d_in[2];
  const float* conv_b    = (const float*)d_in[3];
  const float* x_proj_w  = (const float*)d_in[4];
  const float* dt_proj_w = (const float*)d_in[5];
  const float* dt_proj_b = (const float*)d_in[6];
  const float* A_log     = (const float*)d_in[7];
  const float* Dv        = (const float*)d_in[8];
  const float* out_proj_w= (const float*)d_in[9];
  float* out = (float*)d_out;

  float* ws    = (float*)d_ws;
  float* xz    = ws;                          // [2048][4096] f32
  float* xc    = xz    + (size_t)MM * 4096;   // [2048][2048] f32
  float* xdbl  = xc    + (size_t)MM * DINNER; // [2048][96]   f32
  float* delta = xdbl  + (size_t)MM * 96;     // [2048][2048] f32
  ushort* us   = (ushort*)(delta + (size_t)MM * DINNER);
  ushort* yhp  = us;                           // [2048][2048] bf16 hi
  ushort* ylp  = yhp + (size_t)MM * DINNER;    // repurposed: dt/wd planes
  ushort* xh   = ylp + (size_t)MM * DINNER;    // [2048][1024]
  ushort* xl   = xh  + (size_t)MM * DMODEL;    // (unused)
  ushort* wih  = xl  + (size_t)MM * DMODEL;    // [4096][1024]
  ushort* wil  = wih + (size_t)4096 * DMODEL;
  ushort* woh  = wil + (size_t)4096 * DMODEL;  // [1024][2048]
  ushort* wol  = woh + (size_t)DMODEL * DINNER; // (unused now)

  // dt hi/lo + dt_proj_w hi/lo live in the old yl region (never else used)
  ushort* dth = ylp;
  ushort* dtl = ylp + 131072;
  ushort* wdh = ylp + 262144;
  ushort* wdl = ylp + 393216;

  // hend/aprod/hin (scan) live in wih/wil (dead after in_proj GEMM)
  float* hend  = (float*)wih;
  float* aprod = hend  + (size_t)BB * NCH * DINNER * DSTATE;
  float* hin   = aprod + (size_t)BB * NCH * DINNER * DSTATE;
  // x_proj split-K partials [8][2048][96] = 6.3 MB (consumed before scan)
  float* part  = hend;
  // out_proj split-K partials [4][2048][1024] f32 = 33.55 MB: the xz region
  // (dead after scan_apply reads the z half)
  float* opart = xz;

  const dim3 blk(256);

  // 0) fused precision splits (x hi-only, in_proj_w hi+lo, out_proj_w hi-only,
  //    dt_proj_w hi+lo)
  {
    const int n0 = (MM * DMODEL) / 4, n1 = (4096 * DMODEL) / 4,
              n2 = (DMODEL * DINNER) / 4, n3 = (DINNER * DTRANK) / 4;
    split3<<<dim3((n0 + n1 + n2 + n3) / 256), blk, 0, stream>>>(
        x, xh, nullptr, n0, in_proj_w, wih, wil, n1,
        out_proj_w, woh, nullptr, n2, dt_proj_w, wdh, wdl, n3);
  }

  // 1) in_proj (A-direct 2-product + fused z-gate silu): xz = x @ in_proj_w^T
  gemm_adirect<2, false, 2, 1><<<dim3(4096 / 128, MM / 128), blk, 0, stream>>>(
      xh, nullptr, wih, wil, xz, nullptr, MM, 4096, DMODEL);

  // 2) causal depthwise conv + silu -> xc
  conv_silu<<<dim3((MM * DINNER / 4) / 256), blk, 0, stream>>>(xz, conv_w, conv_b, xc);

  // 3) x_proj split-K + fused reduce/dt-split
  gemm_nt_part<64,32,4,2,256><<<dim3(96/32, MM/64, 8), blk, 0, stream>>>(
      xc, x_proj_w, part, MM, 96, DINNER, DINNER);
  xpr_fused<<<dim3((MM * 24 + 255) / 256), blk, 0, stream>>>(part, xdbl, dth, dtl);

  // 4) dt_proj (A-direct 3-product + softplus): delta = sp(dt @ dt_proj_w^T + b)
  gemm_adirect<2, true, 1, 1><<<dim3(DINNER / 128, MM / 128), blk, 0, stream>>>(
      dth, dtl, wdh, wdl, delta, dt_proj_b, MM, DINNER, DTRANK);

  // 5) chunked parallel scan
  scan_chunk_state<<<dim3(BB * 128 * NCH), dim3(64), 0, stream>>>(
      delta, xc, xdbl, A_log, hend, aprod);
  scan_combine<<<dim3(BB * DINNER * DSTATE / 256), blk, 0, stream>>>(
      hend, aprod, hin);
  scan_apply<<<dim3(BB * 128 * NCH), dim3(64), 0, stream>>>(
      delta, xc, xdbl, xz, A_log, Dv, hin, yhp);

  // 6) out_proj (A-direct 1-product bf16, split-K=4): out = y @ out_proj_w^T
  gemm_adirect<1, false, 0, 4><<<dim3(DMODEL / 128, MM / 128, 4), blk, 0, stream>>>(
      yhp, nullptr, woh, nullptr, opart, nullptr, MM, DMODEL, DINNER);
  splitk_reduce4<<<dim3((MM * DMODEL) / 1024), blk, 0, stream>>>(
      opart, out, MM * DMODEL);
}

// Round 11
// 178.733 us; speedup vs baseline: 1.1113x; 1.1113x over previous
//
#include <hip/hip_runtime.h>
#include <math.h>
#include <stdint.h>

#define DMODEL 1024
#define DINNER 2048
#define DCONV  4
#define DSTATE 16
#define DTRANK 64
#define BB 2
#define LL 1024
#define MM (BB * LL)            // 2048 rows in all GEMMs

#define CL  64                  // scan chunk length
#define NCH (LL / CL)           // 16 chunks

#define AS1(p) ((__attribute__((address_space(1))) void*)(void*)(p))
#define AS3(p) ((__attribute__((address_space(3))) void*)(void*)(p))

typedef __attribute__((ext_vector_type(8))) short bf16x8;
typedef __attribute__((ext_vector_type(4))) float f32x4;

__device__ __forceinline__ ushort bf16_rne(float f) {
  uint32_t u = __float_as_uint(f);
  uint32_t r = (u + 0x7fffu + ((u >> 16) & 1u)) >> 16;
  return (ushort)r;
}

// ---------------------------------------------------------------------------
// Fused f32 -> (hi[, lo]) bf16 split for 4 arrays in one launch.
// ---------------------------------------------------------------------------
__device__ __forceinline__ void split4(const float* __restrict__ in,
                                       ushort* __restrict__ hi,
                                       ushort* __restrict__ lo, int i4) {
  const float4 v = *reinterpret_cast<const float4*>(in + (size_t)i4 * 4);
  ushort4 h;
  h.x = bf16_rne(v.x); h.y = bf16_rne(v.y);
  h.z = bf16_rne(v.z); h.w = bf16_rne(v.w);
  *reinterpret_cast<ushort4*>(hi + (size_t)i4 * 4) = h;
  if (lo) {
    ushort4 l;
    l.x = bf16_rne(v.x - __uint_as_float((uint)h.x << 16));
    l.y = bf16_rne(v.y - __uint_as_float((uint)h.y << 16));
    l.z = bf16_rne(v.z - __uint_as_float((uint)h.z << 16));
    l.w = bf16_rne(v.w - __uint_as_float((uint)h.w << 16));
    *reinterpret_cast<ushort4*>(lo + (size_t)i4 * 4) = l;
  }
}

__global__ __launch_bounds__(256)
void split3(const float* s0, ushort* h0, ushort* l0, int n0,
            const float* s1, ushort* h1, ushort* l1, int n1,
            const float* s2, ushort* h2, ushort* l2, int n2,
            const float* s3, ushort* h3, ushort* l3, int n3) {
  int i = blockIdx.x * 256 + threadIdx.x;
  if (i < n0) { split4(s0, h0, l0, i); return; }
  i -= n0;
  if (i < n1) { split4(s1, h1, l1, i); return; }
  i -= n1;
  if (i < n2) { split4(s2, h2, l2, i); return; }
  i -= n2;
  if (i < n3) { split4(s3, h3, l3, i); return; }
}

__device__ __forceinline__ int swz4(int r) { return (r & 3) ^ ((r >> 2) & 3); }

// ---------------------------------------------------------------------------
// Split-precision bf16 MFMA NT GEMM (3-product), 2-phase double-buffered.
// Used only for dt_proj.  EPI 1: C=softplus(acc+bias[n]).
// ---------------------------------------------------------------------------
template<int EPI, int SPLITK>
__global__ __launch_bounds__(256)
void gemm_hl_mfma(const ushort* __restrict__ Ahg, const ushort* __restrict__ Alg,
                  const ushort* __restrict__ Bhg, const ushort* __restrict__ Blg,
                  float* __restrict__ C, const float* __restrict__ bias,
                  int M, int N, int K) {
  __shared__ ushort Ah[2][128][32];
  __shared__ ushort Al[2][128][32];
  __shared__ ushort Bh[2][128][32];
  __shared__ ushort Bl[2][128][32];

  const int tid  = threadIdx.x;
  const int wave = tid >> 6;
  const int lane = tid & 63;
  const int m0 = blockIdx.y * 128;
  const int n0 = blockIdx.x * 128;
  const int wm = (wave >> 1) * 64;
  const int wn = (wave & 1) * 64;

  const int ksl = K / SPLITK;
  const int kb  = blockIdx.z * ksl;
  float* Cout   = C + (size_t)blockIdx.z * M * N;

  f32x4 acc[4][4];
  #pragma unroll
  for (int i = 0; i < 4; ++i)
    #pragma unroll
    for (int j = 0; j < 4; ++j)
      acc[i][j] = (f32x4){0.f, 0.f, 0.f, 0.f};

  const ushort* gsrc; ushort* dst; int row0;
  if      (wave == 0) { gsrc = Ahg; dst = &Ah[0][0][0]; row0 = m0; }
  else if (wave == 1) { gsrc = Alg; dst = &Al[0][0][0]; row0 = m0; }
  else if (wave == 2) { gsrc = Bhg; dst = &Bh[0][0][0]; row0 = n0; }
  else                { gsrc = Blg; dst = &Bl[0][0][0]; row0 = n0; }

  const int lr = lane >> 2;
  const int ls = lane & 3;
  const int fr = lane & 15;
  const int q  = lane >> 4;

  auto STAGE = [&](int bi, int k0) {
    ushort* d = dst + bi * 4096;
    #pragma unroll
    for (int seg = 0; seg < 8; ++seg) {
      const int rho = seg * 16 + lr;
      const int ks  = (ls ^ swz4(rho)) * 8;
      __builtin_amdgcn_global_load_lds(
          AS1(gsrc + (size_t)(row0 + rho) * K + k0 + ks),
          AS3(d + seg * 512), 16, 0, 0);
    }
  };

  const int NT = ksl / 32;
  STAGE(0, kb);
  __syncthreads();

  int cur = 0;
  for (int kt = 0; kt < NT; ++kt) {
    if (kt + 1 < NT) STAGE(cur ^ 1, kb + (kt + 1) * 32);

    bf16x8 ah[4], al[4], bh[4], bl[4];
    #pragma unroll
    for (int f = 0; f < 4; ++f) {
      { const int r = wm + f * 16 + fr; const int s = 8 * (q ^ swz4(r));
        ah[f] = *reinterpret_cast<const bf16x8*>(&Ah[cur][r][s]);
        al[f] = *reinterpret_cast<const bf16x8*>(&Al[cur][r][s]); }
      { const int r = wn + f * 16 + fr; const int s = 8 * (q ^ swz4(r));
        bh[f] = *reinterpret_cast<const bf16x8*>(&Bh[cur][r][s]);
        bl[f] = *reinterpret_cast<const bf16x8*>(&Bl[cur][r][s]); }
    }
    #pragma unroll
    for (int i = 0; i < 4; ++i)
      #pragma unroll
      for (int j = 0; j < 4; ++j) {
        acc[i][j] = __builtin_amdgcn_mfma_f32_16x16x32_bf16(ah[i], bh[j], acc[i][j], 0, 0, 0);
        acc[i][j] = __builtin_amdgcn_mfma_f32_16x16x32_bf16(al[i], bh[j], acc[i][j], 0, 0, 0);
        acc[i][j] = __builtin_amdgcn_mfma_f32_16x16x32_bf16(ah[i], bl[j], acc[i][j], 0, 0, 0);
      }

    __syncthreads();
    cur ^= 1;
  }

  const int cr = (lane >> 4) * 4;
  const int cc = lane & 15;
  #pragma unroll
  for (int i = 0; i < 4; ++i)
    #pragma unroll
    for (int j = 0; j < 4; ++j) {
      const int cn = n0 + wn + j * 16 + cc;
      const float bj = (EPI == 1) ? bias[cn] : 0.f;
      const size_t base = (size_t)(m0 + wm + i * 16 + cr) * N + cn;
      #pragma unroll
      for (int r = 0; r < 4; ++r) {
        float v = acc[i][j][r];
        if (EPI == 1) {
          v += bj;
          v = fmaxf(v, 0.f) + __logf(1.f + __expf(-fabsf(v)));   // softplus
        }
        Cout[base + (size_t)r * N] = v;
      }
    }
}

// ---------------------------------------------------------------------------
// 2-product MFMA NT GEMM (in_proj): C = Ah @ (Bh+Bl)^T, 3 staged planes,
// 48 KB LDS, 2-phase double-buffered.  EPI 2: silu for cn >= DINNER.
// ---------------------------------------------------------------------------
template<int EPI, int SPLITK>
__global__ __launch_bounds__(256)
void gemm_p2_mfma(const ushort* __restrict__ Ahg, const ushort* __restrict__ Bhg,
                  const ushort* __restrict__ Blg, float* __restrict__ P,
                  int M, int N, int K) {
  __shared__ ushort Ah[2][128][32];
  __shared__ ushort Bh[2][128][32];
  __shared__ ushort Bl[2][128][32];

  const int tid  = threadIdx.x;
  const int wave = tid >> 6;
  const int lane = tid & 63;
  const int m0 = blockIdx.y * 128;
  const int n0 = blockIdx.x * 128;
  const int wm = (wave >> 1) * 64;
  const int wn = (wave & 1) * 64;

  const int ksl = K / SPLITK;
  const int kb  = blockIdx.z * ksl;
  float* Cout   = P + (size_t)blockIdx.z * M * N;

  f32x4 acc[4][4];
  #pragma unroll
  for (int i = 0; i < 4; ++i)
    #pragma unroll
    for (int j = 0; j < 4; ++j)
      acc[i][j] = (f32x4){0.f, 0.f, 0.f, 0.f};

  const ushort* gsrc = nullptr; ushort* dst = nullptr; int row0 = 0;
  if      (wave == 0) { gsrc = Ahg; dst = &Ah[0][0][0]; row0 = m0; }
  else if (wave == 1) { gsrc = Bhg; dst = &Bh[0][0][0]; row0 = n0; }
  else if (wave == 2) { gsrc = Blg; dst = &Bl[0][0][0]; row0 = n0; }

  const int lr = lane >> 2;
  const int ls = lane & 3;
  const int fr = lane & 15;
  const int q  = lane >> 4;

  auto STAGE = [&](int bi, int k0) {
    if (wave >= 3) return;
    ushort* d = dst + bi * 4096;
    #pragma unroll
    for (int seg = 0; seg < 8; ++seg) {
      const int rho = seg * 16 + lr;
      const int ks  = (ls ^ swz4(rho)) * 8;
      __builtin_amdgcn_global_load_lds(
          AS1(gsrc + (size_t)(row0 + rho) * K + k0 + ks),
          AS3(d + seg * 512), 16, 0, 0);
    }
  };

  const int NT = ksl / 32;
  STAGE(0, kb);
  __syncthreads();

  int cur = 0;
  for (int kt = 0; kt < NT; ++kt) {
    if (kt + 1 < NT) STAGE(cur ^ 1, kb + (kt + 1) * 32);

    bf16x8 ah[4], bh[4], bl[4];
    #pragma unroll
    for (int f = 0; f < 4; ++f) {
      { const int r = wm + f * 16 + fr; const int s = 8 * (q ^ swz4(r));
        ah[f] = *reinterpret_cast<const bf16x8*>(&Ah[cur][r][s]); }
      { const int r = wn + f * 16 + fr; const int s = 8 * (q ^ swz4(r));
        bh[f] = *reinterpret_cast<const bf16x8*>(&Bh[cur][r][s]);
        bl[f] = *reinterpret_cast<const bf16x8*>(&Bl[cur][r][s]); }
    }
    #pragma unroll
    for (int i = 0; i < 4; ++i)
      #pragma unroll
      for (int j = 0; j < 4; ++j) {
        acc[i][j] = __builtin_amdgcn_mfma_f32_16x16x32_bf16(ah[i], bh[j], acc[i][j], 0, 0, 0);
        acc[i][j] = __builtin_amdgcn_mfma_f32_16x16x32_bf16(ah[i], bl[j], acc[i][j], 0, 0, 0);
      }

    __syncthreads();
    cur ^= 1;
  }

  const int cr = (lane >> 4) * 4;
  const int cc = lane & 15;
  #pragma unroll
  for (int i = 0; i < 4; ++i)
    #pragma unroll
    for (int j = 0; j < 4; ++j) {
      const int cn = n0 + wn + j * 16 + cc;
      const size_t base = (size_t)(m0 + wm + i * 16 + cr) * N + cn;
      #pragma unroll
      for (int r = 0; r < 4; ++r) {
        float v = acc[i][j][r];
        if (EPI == 2 && cn >= DINNER)
          v = v / (1.f + __expf(-v));     // silu: z-gate precompute
        Cout[base + (size_t)r * N] = v;
      }
    }
}

// ---------------------------------------------------------------------------
// 1-product MFMA NT GEMM (out_proj): C = Ah @ Bh^T, 2 staged planes,
// 32 KB LDS, 2-phase double-buffered, SPLITK via blockIdx.z.
// ---------------------------------------------------------------------------
template<int SPLITK>
__global__ __launch_bounds__(256)
void gemm_p1_mfma(const ushort* __restrict__ Ahg, const ushort* __restrict__ Bhg,
                  float* __restrict__ P, int M, int N, int K) {
  __shared__ ushort Ah[2][128][32];
  __shared__ ushort Bh[2][128][32];

  const int tid  = threadIdx.x;
  const int wave = tid >> 6;
  const int lane = tid & 63;
  const int m0 = blockIdx.y * 128;
  const int n0 = blockIdx.x * 128;
  const int wm = (wave >> 1) * 64;
  const int wn = (wave & 1) * 64;

  const int ksl = K / SPLITK;
  const int kb  = blockIdx.z * ksl;
  float* Cout   = P + (size_t)blockIdx.z * M * N;

  f32x4 acc[4][4];
  #pragma unroll
  for (int i = 0; i < 4; ++i)
    #pragma unroll
    for (int j = 0; j < 4; ++j)
      acc[i][j] = (f32x4){0.f, 0.f, 0.f, 0.f};

  const ushort* gsrc = nullptr; ushort* dst = nullptr; int row0 = 0;
  if      (wave == 0) { gsrc = Ahg; dst = &Ah[0][0][0]; row0 = m0; }
  else if (wave == 1) { gsrc = Bhg; dst = &Bh[0][0][0]; row0 = n0; }

  const int lr = lane >> 2;
  const int ls = lane & 3;
  const int fr = lane & 15;
  const int q  = lane >> 4;

  auto STAGE = [&](int bi, int k0) {
    if (wave >= 2) return;
    ushort* d = dst + bi * 4096;
    #pragma unroll
    for (int seg = 0; seg < 8; ++seg) {
      const int rho = seg * 16 + lr;
      const int ks  = (ls ^ swz4(rho)) * 8;
      __builtin_amdgcn_global_load_lds(
          AS1(gsrc + (size_t)(row0 + rho) * K + k0 + ks),
          AS3(d + seg * 512), 16, 0, 0);
    }
  };

  const int NT = ksl / 32;
  STAGE(0, kb);
  __syncthreads();

  int cur = 0;
  for (int kt = 0; kt < NT; ++kt) {
    if (kt + 1 < NT) STAGE(cur ^ 1, kb + (kt + 1) * 32);

    bf16x8 ah[4], bh[4];
    #pragma unroll
    for (int f = 0; f < 4; ++f) {
      { const int r = wm + f * 16 + fr; const int s = 8 * (q ^ swz4(r));
        ah[f] = *reinterpret_cast<const bf16x8*>(&Ah[cur][r][s]); }
      { const int r = wn + f * 16 + fr; const int s = 8 * (q ^ swz4(r));
        bh[f] = *reinterpret_cast<const bf16x8*>(&Bh[cur][r][s]); }
    }
    #pragma unroll
    for (int i = 0; i < 4; ++i)
      #pragma unroll
      for (int j = 0; j < 4; ++j)
        acc[i][j] = __builtin_amdgcn_mfma_f32_16x16x32_bf16(ah[i], bh[j], acc[i][j], 0, 0, 0);

    __syncthreads();
    cur ^= 1;
  }

  const int cr = (lane >> 4) * 4;
  const int cc = lane & 15;
  #pragma unroll
  for (int i = 0; i < 4; ++i)
    #pragma unroll
    for (int j = 0; j < 4; ++j) {
      const size_t base = (size_t)(m0 + wm + i * 16 + cr) * N + (n0 + wn + j * 16 + cc);
      #pragma unroll
      for (int r = 0; r < 4; ++r)
        Cout[base + (size_t)r * N] = acc[i][j][r];
    }
}

// sum 4 split-K partial planes -> out
__global__ __launch_bounds__(256)
void splitk_reduce4(const float* __restrict__ P, float* __restrict__ out, int n) {
  const int i = (blockIdx.x * 256 + threadIdx.x) * 4;
  if (i >= n) return;
  float4 s = *reinterpret_cast<const float4*>(P + i);
  #pragma unroll
  for (int z = 1; z < 4; ++z) {
    const float4 v = *reinterpret_cast<const float4*>(P + (size_t)z * n + i);
    s.x += v.x; s.y += v.y; s.z += v.z; s.w += v.w;
  }
  *reinterpret_cast<float4*>(out + i) = s;
}

// ---------------------------------------------------------------------------
// Split-K f32 NT GEMM partials (x_proj)
// ---------------------------------------------------------------------------
template<int BM, int BN, int TM, int TN, int KSLICE>
__global__ __launch_bounds__(256)
void gemm_nt_part(const float* __restrict__ A, const float* __restrict__ Bw,
                  float* __restrict__ P, int M, int N, int lda, int ldb) {
  constexpr int BK  = 16;
  constexpr int NTX = BN / TN;
  constexpr int NTY = BM / TM;
  static_assert(NTX * NTY == 256, "thread tile mismatch");
  __shared__ float As[BK][BM + 4];
  __shared__ float Bs[BK][BN + 4];

  const int tid = threadIdx.x;
  const int m0  = blockIdx.y * BM;
  const int n0  = blockIdx.x * BN;
  const int kb  = blockIdx.z * KSLICE;
  const int tx  = tid % NTX;
  const int ty  = tid / NTX;

  float acc[TM][TN] = {};

  for (int k0 = kb; k0 < kb + KSLICE; k0 += BK) {
    __syncthreads();
    for (int t = tid; t < BM * 4; t += 256) {
      const int row = t >> 2, kq = t & 3;
      const float4 v = *reinterpret_cast<const float4*>(
          A + (size_t)(m0 + row) * lda + k0 + kq * 4);
      As[kq * 4 + 0][row] = v.x;
      As[kq * 4 + 1][row] = v.y;
      As[kq * 4 + 2][row] = v.z;
      As[kq * 4 + 3][row] = v.w;
    }
    for (int t = tid; t < BN * 4; t += 256) {
      const int row = t >> 2, kq = t & 3;
      const float4 v = *reinterpret_cast<const float4*>(
          Bw + (size_t)(n0 + row) * ldb + k0 + kq * 4);
      Bs[kq * 4 + 0][row] = v.x;
      Bs[kq * 4 + 1][row] = v.y;
      Bs[kq * 4 + 2][row] = v.z;
      Bs[kq * 4 + 3][row] = v.w;
    }
    __syncthreads();
    #pragma unroll
    for (int k = 0; k < BK; ++k) {
      float a[TM], b[TN];
      #pragma unroll
      for (int i = 0; i < TM; ++i) a[i] = As[k][ty * TM + i];
      #pragma unroll
      for (int j = 0; j < TN; ++j) b[j] = Bs[k][tx * TN + j];
      #pragma unroll
      for (int i = 0; i < TM; ++i)
        #pragma unroll
        for (int j = 0; j < TN; ++j)
          acc[i][j] = fmaf(a[i], b[j], acc[i][j]);
    }
  }

  float* out = P + (size_t)blockIdx.z * M * N;
  #pragma unroll
  for (int i = 0; i < TM; ++i)
    #pragma unroll
    for (int j = 0; j < TN; ++j)
      out[(size_t)(m0 + ty * TM + i) * N + n0 + tx * TN + j] = acc[i][j];
}

// reduce x_proj partials; dt cols (0..63) -> packed bf16 hi/lo, B/C cols -> f32
__global__ __launch_bounds__(256)
void xpr_fused(const float* __restrict__ part, float* __restrict__ xdbl,
               ushort* __restrict__ dth, ushort* __restrict__ dtl) {
  const int i = blockIdx.x * 256 + threadIdx.x;   // float4 over [2048][24]
  if (i >= MM * 24) return;
  const int m  = i / 24;
  const int c4 = (i % 24) * 4;
  const size_t off = (size_t)m * 96 + c4;
  float4 s = *reinterpret_cast<const float4*>(part + off);
  #pragma unroll
  for (int z = 1; z < 8; ++z) {
    const float4 v = *reinterpret_cast<const float4*>(part + (size_t)z * MM * 96 + off);
    s.x += v.x; s.y += v.y; s.z += v.z; s.w += v.w;
  }
  if (c4 < 64) {
    ushort4 h, l;
    h.x = bf16_rne(s.x); l.x = bf16_rne(s.x - __uint_as_float((uint)h.x << 16));
    h.y = bf16_rne(s.y); l.y = bf16_rne(s.y - __uint_as_float((uint)h.y << 16));
    h.z = bf16_rne(s.z); l.z = bf16_rne(s.z - __uint_as_float((uint)h.z << 16));
    h.w = bf16_rne(s.w); l.w = bf16_rne(s.w - __uint_as_float((uint)h.w << 16));
    *reinterpret_cast<ushort4*>(dth + (size_t)m * 64 + c4) = h;
    *reinterpret_cast<ushort4*>(dtl + (size_t)m * 64 + c4) = l;
  } else {
    *reinterpret_cast<float4*>(xdbl + off) = s;
  }
}

// ---------------------------------------------------------------------------
// Depthwise causal conv1d (k=4) + bias + SiLU, float4-vectorized.
// ---------------------------------------------------------------------------
__global__ __launch_bounds__(256)
void conv_silu(const float* __restrict__ xz, const float* __restrict__ cw,
               const float* __restrict__ cb, float* __restrict__ xc) {
  const int idx = blockIdx.x * 256 + threadIdx.x;   // over MM*DINNER/4
  if (idx >= MM * DINNER / 4) return;
  const int d4 = (idx & 511) * 4;       // DINNER/4 = 512 per row
  const int m  = idx >> 9;
  const int l  = m & (LL - 1);
  const int b  = m >> 10;

  float4 w0 = *reinterpret_cast<const float4*>(cw + (size_t)(d4 + 0) * 4);
  float4 w1 = *reinterpret_cast<const float4*>(cw + (size_t)(d4 + 1) * 4);
  float4 w2 = *reinterpret_cast<const float4*>(cw + (size_t)(d4 + 2) * 4);
  float4 w3 = *reinterpret_cast<const float4*>(cw + (size_t)(d4 + 3) * 4);
  float4 acc = *reinterpret_cast<const float4*>(cb + d4);

  #pragma unroll
  for (int j = 0; j < DCONV; ++j) {
    const int ll = l - (DCONV - 1) + j;
    if (ll >= 0) {
      const float4 xv = *reinterpret_cast<const float4*>(
          xz + ((size_t)(b * LL + ll) << 12) + d4);
      acc.x = fmaf(xv.x, (&w0.x)[j], acc.x);
      acc.y = fmaf(xv.y, (&w1.x)[j], acc.y);
      acc.z = fmaf(xv.z, (&w2.x)[j], acc.z);
      acc.w = fmaf(xv.w, (&w3.x)[j], acc.w);
    }
  }
  float4 o;
  o.x = acc.x / (1.f + __expf(-acc.x));
  o.y = acc.y / (1.f + __expf(-acc.y));
  o.z = acc.z / (1.f + __expf(-acc.z));
  o.w = acc.w / (1.f + __expf(-acc.w));
  *reinterpret_cast<float4*>(xc + (size_t)m * DINNER + d4) = o;
}

// ---------------------------------------------------------------------------
// Chunked parallel selective scan (3 passes).
// ---------------------------------------------------------------------------
__device__ __forceinline__ void stage_tile(const float* g, int stride,
                                           float* ldst, int lane) {
  const int r  = lane >> 2;
  const int q4 = (lane & 3) * 4;
  #pragma unroll
  for (int i = 0; i < 4; ++i) {
    __builtin_amdgcn_global_load_lds(
        AS1(g + (size_t)(i * 16 + r) * stride + q4),
        AS3(ldst + i * 256), 16, 0, 0);
  }
}

__device__ __forceinline__ float quad_sum(float v) {
  int i = __float_as_int(v);
  v += __int_as_float(__builtin_amdgcn_update_dpp(0, i, 0xB1, 0xf, 0xf, true)); // xor 1
  i = __float_as_int(v);
  v += __int_as_float(__builtin_amdgcn_update_dpp(0, i, 0x4E, 0xf, 0xf, true)); // xor 2
  return v;
}

__global__ __launch_bounds__(64)
void scan_chunk_state(const float* __restrict__ delta, const float* __restrict__ xc,
                      const float* __restrict__ xdbl, const float* __restrict__ A_log,
                      float* __restrict__ hend, float* __restrict__ aprod) {
  __shared__ float dT[CL][16];
  __shared__ float xT[CL][16];
  __shared__ float bT[CL][16];

  const int idx = blockIdx.x;          // (b*128 + dg)*16 + c
  const int c  = idx & 15;
  const int dg = (idx >> 4) & 127;
  const int b  = idx >> 11;
  const int t  = threadIdx.x;
  const int ch = t >> 2;
  const int q  = t & 3;
  const int d  = dg * 16 + ch;

  const size_t r0 = (size_t)b * LL + (size_t)c * CL;
  stage_tile(delta + r0 * DINNER + dg * 16, DINNER, &dT[0][0], t);
  stage_tile(xc    + r0 * DINNER + dg * 16, DINNER, &xT[0][0], t);
  stage_tile(xdbl  + r0 * 96 + DTRANK,          96, &bT[0][0], t);

  float Adn[4];
  #pragma unroll
  for (int j = 0; j < 4; ++j)
    Adn[j] = -__expf(A_log[d * DSTATE + 4 * q + j]);
  float h0 = 0.f, h1 = 0.f, h2 = 0.f, h3 = 0.f;
  float p0 = 1.f, p1 = 1.f, p2 = 1.f, p3 = 1.f;

  __syncthreads();

  #pragma unroll 8
  for (int l = 0; l < CL; ++l) {
    const float dv = dT[l][ch];
    const float xv = xT[l][ch];
    const float4 B4 = *reinterpret_cast<const float4*>(&bT[l][4 * q]);
    const float dvx = dv * xv;
    const float a0 = __expf(dv * Adn[0]);
    const float a1 = __expf(dv * Adn[1]);
    const float a2 = __expf(dv * Adn[2]);
    const float a3 = __expf(dv * Adn[3]);
    h0 = fmaf(a0, h0, dvx * B4.x);  p0 *= a0;
    h1 = fmaf(a1, h1, dvx * B4.y);  p1 *= a1;
    h2 = fmaf(a2, h2, dvx * B4.z);  p2 *= a2;
    h3 = fmaf(a3, h3, dvx * B4.w);  p3 *= a3;
  }

  const size_t base = (((size_t)(b * NCH + c) * DINNER) + d) * DSTATE + 4 * q;
  *reinterpret_cast<float4*>(hend  + base) = (float4){h0, h1, h2, h3};
  *reinterpret_cast<float4*>(aprod + base) = (float4){p0, p1, p2, p3};
}

__global__ __launch_bounds__(256)
void scan_combine(const float* __restrict__ hend, const float* __restrict__ aprod,
                  float* __restrict__ hin) {
  const int tid = blockIdx.x * 256 + threadIdx.x;   // 65536 total
  const size_t cstride = (size_t)DINNER * DSTATE;   // 32768
  const size_t base = (size_t)(tid >> 15) * NCH * cstride + (tid & 32767);
  float h = 0.f;
  hin[base] = 0.f;
  #pragma unroll
  for (int c = 0; c < NCH - 1; ++c) {
    h = fmaf(aprod[base + (size_t)c * cstride], h, hend[base + (size_t)c * cstride]);
    hin[base + (size_t)(c + 1) * cstride] = h;
  }
}

__global__ __launch_bounds__(64)
void scan_apply(const float* __restrict__ delta, const float* __restrict__ xc,
                const float* __restrict__ xdbl, const float* __restrict__ xz,
                const float* __restrict__ A_log, const float* __restrict__ Dp,
                const float* __restrict__ hin, ushort* __restrict__ yh) {
  __shared__ float dT[CL][16];
  __shared__ float xT[CL][16];
  __shared__ float bT[CL][16];
  __shared__ float cT[CL][16];
  __shared__ float zT[CL][16];

  const int idx = blockIdx.x;
  const int c  = idx & 15;
  const int dg = (idx >> 4) & 127;
  const int b  = idx >> 11;
  const int t  = threadIdx.x;
  const int ch = t >> 2;
  const int q  = t & 3;
  const int d  = dg * 16 + ch;

  const size_t r0 = (size_t)b * LL + (size_t)c * CL;
  stage_tile(delta + r0 * DINNER + dg * 16, DINNER, &dT[0][0], t);
  stage_tile(xc    + r0 * DINNER + dg * 16, DINNER, &xT[0][0], t);
  stage_tile(xdbl  + r0 * 96 + DTRANK,          96, &bT[0][0], t);
  stage_tile(xdbl  + r0 * 96 + DTRANK + DSTATE, 96, &cT[0][0], t);
  stage_tile(xz    + (r0 << 12) + DINNER + dg * 16, 4096, &zT[0][0], t);

  float Adn[4];
  #pragma unroll
  for (int j = 0; j < 4; ++j)
    Adn[j] = -__expf(A_log[d * DSTATE + 4 * q + j]);
  const float Dd = Dp[d];

  const size_t base = (((size_t)(b * NCH + c) * DINNER) + d) * DSTATE + 4 * q;
  const float4 h4 = *reinterpret_cast<const float4*>(hin + base);
  float h0 = h4.x, h1 = h4.y, h2 = h4.z, h3 = h4.w;

  __syncthreads();

  #pragma unroll 8
  for (int l = 0; l < CL; ++l) {
    const float dv = dT[l][ch];
    const float xv = xT[l][ch];
    const float4 B4 = *reinterpret_cast<const float4*>(&bT[l][4 * q]);
    const float4 C4 = *reinterpret_cast<const float4*>(&cT[l][4 * q]);
    const float dvx = dv * xv;
    const float a0 = __expf(dv * Adn[0]);
    const float a1 = __expf(dv * Adn[1]);
    const float a2 = __expf(dv * Adn[2]);
    const float a3 = __expf(dv * Adn[3]);
    h0 = fmaf(a0, h0, dvx * B4.x);
    h1 = fmaf(a1, h1, dvx * B4.y);
    h2 = fmaf(a2, h2, dvx * B4.z);
    h3 = fmaf(a3, h3, dvx * B4.w);
    float ys = fmaf(h0, C4.x, fmaf(h1, C4.y, fmaf(h2, C4.z, h3 * C4.w)));
    ys = quad_sum(ys);
    if (q == 0) {
      const float g = zT[l][ch];        // silu(z) precomputed by in_proj epilogue
      const float tv = (ys + xv * Dd) * g;
      yh[(r0 + l) * (size_t)DINNER + d] = bf16_rne(tv);
    }
  }
}

// ---------------------------------------------------------------------------
extern "C" void kernel_launch(void* const* d_in, const int* in_sizes, int n_in,
                              void* d_out, int out_size, void* d_ws, size_t ws_size,
                              hipStream_t stream) {
  const float* x         = (const float*)d_in[0];
  const float* in_proj_w = (const float*)d_in[1];
  const float* conv_w    = (const float*)d_in[2];
  const float* conv_b    = (const float*)d_in[3];
  const float* x_proj_w  = (const float*)d_in[4];
  const float* dt_proj_w = (const float*)d_in[5];
  const float* dt_proj_b = (const float*)d_in[6];
  const float* A_log     = (const float*)d_in[7];
  const float* Dv        = (const float*)d_in[8];
  const float* out_proj_w= (const float*)d_in[9];
  float* out = (float*)d_out;

  float* ws    = (float*)d_ws;
  float* xz    = ws;                          // [2048][4096] f32
  float* xc    = xz    + (size_t)MM * 4096;   // [2048][2048] f32
  float* xdbl  = xc    + (size_t)MM * DINNER; // [2048][96]   f32
  float* delta = xdbl  + (size_t)MM * 96;     // [2048][2048] f32
  ushort* us   = (ushort*)(delta + (size_t)MM * DINNER);
  ushort* yhp  = us;                           // [2048][2048] bf16 hi
  ushort* ylp  = yhp + (size_t)MM * DINNER;    // repurposed: dt/wd planes
  ushort* xh   = ylp + (size_t)MM * DINNER;    // [2048][1024]
  ushort* xl   = xh  + (size_t)MM * DMODEL;    // (unused)
  ushort* wih  = xl  + (size_t)MM * DMODEL;    // [4096][1024]
  ushort* wil  = wih + (size_t)4096 * DMODEL;
  ushort* woh  = wil + (size_t)4096 * DMODEL;  // [1024][2048]
  ushort* wol  = woh + (size_t)DMODEL * DINNER; // (unused)

  // dt hi/lo + dt_proj_w hi/lo live in the old yl region (never else used)
  ushort* dth = ylp;
  ushort* dtl = ylp + 131072;
  ushort* wdh = ylp + 262144;
  ushort* wdl = ylp + 393216;

  // hend/aprod/hin (scan) live in wih/wil (dead after in_proj GEMM)
  float* hend  = (float*)wih;
  float* aprod = hend  + (size_t)BB * NCH * DINNER * DSTATE;
  float* hin   = aprod + (size_t)BB * NCH * DINNER * DSTATE;
  // x_proj split-K partials [8][2048][96] = 6.3 MB (consumed before scan)
  float* part  = hend;
  // out_proj split-K partials [4][2048][1024] f32 = 33.55 MB: the xz region
  // (dead after scan_apply reads the z half)
  float* opart = xz;

  const dim3 blk(256);

  // 0) fused precision splits
  {
    const int n0 = (MM * DMODEL) / 4, n1 = (4096 * DMODEL) / 4,
              n2 = (DMODEL * DINNER) / 4, n3 = (DINNER * DTRANK) / 4;
    split3<<<dim3((n0 + n1 + n2 + n3) / 256), blk, 0, stream>>>(
        x, xh, nullptr, n0, in_proj_w, wih, wil, n1,
        out_proj_w, woh, nullptr, n2, dt_proj_w, wdh, wdl, n3);
  }

  // 1) in_proj (2-product MFMA + fused z-gate silu): xz = x @ in_proj_w^T
  gemm_p2_mfma<2,1><<<dim3(4096 / 128, MM / 128), blk, 0, stream>>>(
      xh, wih, wil, xz, MM, 4096, DMODEL);

  // 2) causal depthwise conv + silu -> xc
  conv_silu<<<dim3((MM * DINNER / 4) / 256), blk, 0, stream>>>(xz, conv_w, conv_b, xc);

  // 3) x_proj split-K + fused reduce/dt-split
  gemm_nt_part<64,32,4,2,256><<<dim3(96/32, MM/64, 8), blk, 0, stream>>>(
      xc, x_proj_w, part, MM, 96, DINNER, DINNER);
  xpr_fused<<<dim3((MM * 24 + 255) / 256), blk, 0, stream>>>(part, xdbl, dth, dtl);

  // 4) dt_proj (MFMA split-bf16 3-product + softplus)
  gemm_hl_mfma<1,1><<<dim3(DINNER / 128, MM / 128), blk, 0, stream>>>(
      dth, dtl, wdh, wdl, delta, dt_proj_b, MM, DINNER, DTRANK);

  // 5) chunked parallel scan
  scan_chunk_state<<<dim3(BB * 128 * NCH), dim3(64), 0, stream>>>(
      delta, xc, xdbl, A_log, hend, aprod);
  scan_combine<<<dim3(BB * DINNER * DSTATE / 256), blk, 0, stream>>>(
      hend, aprod, hin);
  scan_apply<<<dim3(BB * 128 * NCH), dim3(64), 0, stream>>>(
      delta, xc, xdbl, xz, A_log, Dv, hin, yhp);

  // 6) out_proj (1-product bf16 MFMA, split-K=4): out = y @ out_proj_w^T
  gemm_p1_mfma<4><<<dim3(DMODEL / 128, MM / 128, 4), blk, 0, stream>>>(
      yhp, woh, opart, MM, DMODEL, DINNER);
  splitk_reduce4<<<dim3((MM * DMODEL) / 1024), blk, 0, stream>>>(
      opart, out, MM * DMODEL);
}

// Round 12
// 167.452 us; speedup vs baseline: 1.1862x; 1.0674x over previous
//
#include <hip/hip_runtime.h>
#include <math.h>
#include <stdint.h>

#define DMODEL 1024
#define DINNER 2048
#define DCONV  4
#define DSTATE 16
#define DTRANK 64
#define BB 2
#define LL 1024
#define MM (BB * LL)            // 2048 rows in all GEMMs

#define CL  64                  // scan chunk length
#define NCH (LL / CL)           // 16 chunks

#define AS1(p) ((__attribute__((address_space(1))) void*)(void*)(p))
#define AS3(p) ((__attribute__((address_space(3))) void*)(void*)(p))

typedef __attribute__((ext_vector_type(8))) short bf16x8;
typedef __attribute__((ext_vector_type(4))) float f32x4;

__device__ __forceinline__ ushort bf16_rne(float f) {
  uint32_t u = __float_as_uint(f);
  uint32_t r = (u + 0x7fffu + ((u >> 16) & 1u)) >> 16;
  return (ushort)r;
}

// ---------------------------------------------------------------------------
// Fused f32 -> (hi[, lo]) bf16 split for 4 arrays in one launch.
// ---------------------------------------------------------------------------
__device__ __forceinline__ void split4(const float* __restrict__ in,
                                       ushort* __restrict__ hi,
                                       ushort* __restrict__ lo, int i4) {
  const float4 v = *reinterpret_cast<const float4*>(in + (size_t)i4 * 4);
  ushort4 h;
  h.x = bf16_rne(v.x); h.y = bf16_rne(v.y);
  h.z = bf16_rne(v.z); h.w = bf16_rne(v.w);
  *reinterpret_cast<ushort4*>(hi + (size_t)i4 * 4) = h;
  if (lo) {
    ushort4 l;
    l.x = bf16_rne(v.x - __uint_as_float((uint)h.x << 16));
    l.y = bf16_rne(v.y - __uint_as_float((uint)h.y << 16));
    l.z = bf16_rne(v.z - __uint_as_float((uint)h.z << 16));
    l.w = bf16_rne(v.w - __uint_as_float((uint)h.w << 16));
    *reinterpret_cast<ushort4*>(lo + (size_t)i4 * 4) = l;
  }
}

__global__ __launch_bounds__(256)
void split3(const float* s0, ushort* h0, ushort* l0, int n0,
            const float* s1, ushort* h1, ushort* l1, int n1,
            const float* s2, ushort* h2, ushort* l2, int n2,
            const float* s3, ushort* h3, ushort* l3, int n3) {
  int i = blockIdx.x * 256 + threadIdx.x;
  if (i < n0) { split4(s0, h0, l0, i); return; }
  i -= n0;
  if (i < n1) { split4(s1, h1, l1, i); return; }
  i -= n1;
  if (i < n2) { split4(s2, h2, l2, i); return; }
  i -= n2;
  if (i < n3) { split4(s3, h3, l3, i); return; }
}

__device__ __forceinline__ int swz4(int r) { return (r & 3) ^ ((r >> 2) & 3); }

// ---------------------------------------------------------------------------
// Split-precision bf16 MFMA NT GEMM (3-product), 2-phase double-buffered.
// Used only for dt_proj (error-critical path).  EPI 1: softplus(acc+bias).
// ---------------------------------------------------------------------------
template<int EPI, int SPLITK>
__global__ __launch_bounds__(256)
void gemm_hl_mfma(const ushort* __restrict__ Ahg, const ushort* __restrict__ Alg,
                  const ushort* __restrict__ Bhg, const ushort* __restrict__ Blg,
                  float* __restrict__ C, const float* __restrict__ bias,
                  int M, int N, int K) {
  __shared__ ushort Ah[2][128][32];
  __shared__ ushort Al[2][128][32];
  __shared__ ushort Bh[2][128][32];
  __shared__ ushort Bl[2][128][32];

  const int tid  = threadIdx.x;
  const int wave = tid >> 6;
  const int lane = tid & 63;
  const int m0 = blockIdx.y * 128;
  const int n0 = blockIdx.x * 128;
  const int wm = (wave >> 1) * 64;
  const int wn = (wave & 1) * 64;

  const int ksl = K / SPLITK;
  const int kb  = blockIdx.z * ksl;
  float* Cout   = C + (size_t)blockIdx.z * M * N;

  f32x4 acc[4][4];
  #pragma unroll
  for (int i = 0; i < 4; ++i)
    #pragma unroll
    for (int j = 0; j < 4; ++j)
      acc[i][j] = (f32x4){0.f, 0.f, 0.f, 0.f};

  const ushort* gsrc; ushort* dst; int row0;
  if      (wave == 0) { gsrc = Ahg; dst = &Ah[0][0][0]; row0 = m0; }
  else if (wave == 1) { gsrc = Alg; dst = &Al[0][0][0]; row0 = m0; }
  else if (wave == 2) { gsrc = Bhg; dst = &Bh[0][0][0]; row0 = n0; }
  else                { gsrc = Blg; dst = &Bl[0][0][0]; row0 = n0; }

  const int lr = lane >> 2;
  const int ls = lane & 3;
  const int fr = lane & 15;
  const int q  = lane >> 4;

  auto STAGE = [&](int bi, int k0) {
    ushort* d = dst + bi * 4096;
    #pragma unroll
    for (int seg = 0; seg < 8; ++seg) {
      const int rho = seg * 16 + lr;
      const int ks  = (ls ^ swz4(rho)) * 8;
      __builtin_amdgcn_global_load_lds(
          AS1(gsrc + (size_t)(row0 + rho) * K + k0 + ks),
          AS3(d + seg * 512), 16, 0, 0);
    }
  };

  const int NT = ksl / 32;
  STAGE(0, kb);
  __syncthreads();

  int cur = 0;
  for (int kt = 0; kt < NT; ++kt) {
    if (kt + 1 < NT) STAGE(cur ^ 1, kb + (kt + 1) * 32);

    bf16x8 ah[4], al[4], bh[4], bl[4];
    #pragma unroll
    for (int f = 0; f < 4; ++f) {
      { const int r = wm + f * 16 + fr; const int s = 8 * (q ^ swz4(r));
        ah[f] = *reinterpret_cast<const bf16x8*>(&Ah[cur][r][s]);
        al[f] = *reinterpret_cast<const bf16x8*>(&Al[cur][r][s]); }
      { const int r = wn + f * 16 + fr; const int s = 8 * (q ^ swz4(r));
        bh[f] = *reinterpret_cast<const bf16x8*>(&Bh[cur][r][s]);
        bl[f] = *reinterpret_cast<const bf16x8*>(&Bl[cur][r][s]); }
    }
    #pragma unroll
    for (int i = 0; i < 4; ++i)
      #pragma unroll
      for (int j = 0; j < 4; ++j) {
        acc[i][j] = __builtin_amdgcn_mfma_f32_16x16x32_bf16(ah[i], bh[j], acc[i][j], 0, 0, 0);
        acc[i][j] = __builtin_amdgcn_mfma_f32_16x16x32_bf16(al[i], bh[j], acc[i][j], 0, 0, 0);
        acc[i][j] = __builtin_amdgcn_mfma_f32_16x16x32_bf16(ah[i], bl[j], acc[i][j], 0, 0, 0);
      }

    __syncthreads();
    cur ^= 1;
  }

  const int cr = (lane >> 4) * 4;
  const int cc = lane & 15;
  #pragma unroll
  for (int i = 0; i < 4; ++i)
    #pragma unroll
    for (int j = 0; j < 4; ++j) {
      const int cn = n0 + wn + j * 16 + cc;
      const float bj = (EPI == 1) ? bias[cn] : 0.f;
      const size_t base = (size_t)(m0 + wm + i * 16 + cr) * N + cn;
      #pragma unroll
      for (int r = 0; r < 4; ++r) {
        float v = acc[i][j][r];
        if (EPI == 1) {
          v += bj;
          v = fmaxf(v, 0.f) + __logf(1.f + __expf(-fabsf(v)));   // softplus
        }
        Cout[base + (size_t)r * N] = v;
      }
    }
}

// ---------------------------------------------------------------------------
// 1-product MFMA NT GEMM: C = Ah @ Bh^T, 2 staged planes, 32 KB LDS,
// 2-phase double-buffered, SPLITK via blockIdx.z.
// EPI 0: plain.  EPI 2: silu for columns cn >= DINNER (in_proj z-gate).
// ---------------------------------------------------------------------------
template<int EPI, int SPLITK>
__global__ __launch_bounds__(256)
void gemm_p1_mfma(const ushort* __restrict__ Ahg, const ushort* __restrict__ Bhg,
                  float* __restrict__ P, int M, int N, int K) {
  __shared__ ushort Ah[2][128][32];
  __shared__ ushort Bh[2][128][32];

  const int tid  = threadIdx.x;
  const int wave = tid >> 6;
  const int lane = tid & 63;
  const int m0 = blockIdx.y * 128;
  const int n0 = blockIdx.x * 128;
  const int wm = (wave >> 1) * 64;
  const int wn = (wave & 1) * 64;

  const int ksl = K / SPLITK;
  const int kb  = blockIdx.z * ksl;
  float* Cout   = P + (size_t)blockIdx.z * M * N;

  f32x4 acc[4][4];
  #pragma unroll
  for (int i = 0; i < 4; ++i)
    #pragma unroll
    for (int j = 0; j < 4; ++j)
      acc[i][j] = (f32x4){0.f, 0.f, 0.f, 0.f};

  const ushort* gsrc = nullptr; ushort* dst = nullptr; int row0 = 0;
  if      (wave == 0) { gsrc = Ahg; dst = &Ah[0][0][0]; row0 = m0; }
  else if (wave == 1) { gsrc = Bhg; dst = &Bh[0][0][0]; row0 = n0; }

  const int lr = lane >> 2;
  const int ls = lane & 3;
  const int fr = lane & 15;
  const int q  = lane >> 4;

  auto STAGE = [&](int bi, int k0) {
    if (wave >= 2) return;
    ushort* d = dst + bi * 4096;
    #pragma unroll
    for (int seg = 0; seg < 8; ++seg) {
      const int rho = seg * 16 + lr;
      const int ks  = (ls ^ swz4(rho)) * 8;
      __builtin_amdgcn_global_load_lds(
          AS1(gsrc + (size_t)(row0 + rho) * K + k0 + ks),
          AS3(d + seg * 512), 16, 0, 0);
    }
  };

  const int NT = ksl / 32;
  STAGE(0, kb);
  __syncthreads();

  int cur = 0;
  for (int kt = 0; kt < NT; ++kt) {
    if (kt + 1 < NT) STAGE(cur ^ 1, kb + (kt + 1) * 32);

    bf16x8 ah[4], bh[4];
    #pragma unroll
    for (int f = 0; f < 4; ++f) {
      { const int r = wm + f * 16 + fr; const int s = 8 * (q ^ swz4(r));
        ah[f] = *reinterpret_cast<const bf16x8*>(&Ah[cur][r][s]); }
      { const int r = wn + f * 16 + fr; const int s = 8 * (q ^ swz4(r));
        bh[f] = *reinterpret_cast<const bf16x8*>(&Bh[cur][r][s]); }
    }
    #pragma unroll
    for (int i = 0; i < 4; ++i)
      #pragma unroll
      for (int j = 0; j < 4; ++j)
        acc[i][j] = __builtin_amdgcn_mfma_f32_16x16x32_bf16(ah[i], bh[j], acc[i][j], 0, 0, 0);

    __syncthreads();
    cur ^= 1;
  }

  const int cr = (lane >> 4) * 4;
  const int cc = lane & 15;
  #pragma unroll
  for (int i = 0; i < 4; ++i)
    #pragma unroll
    for (int j = 0; j < 4; ++j) {
      const int cn = n0 + wn + j * 16 + cc;
      const size_t base = (size_t)(m0 + wm + i * 16 + cr) * N + cn;
      #pragma unroll
      for (int r = 0; r < 4; ++r) {
        float v = acc[i][j][r];
        if (EPI == 2 && cn >= DINNER)
          v = v / (1.f + __expf(-v));     // silu: z-gate precompute
        Cout[base + (size_t)r * N] = v;
      }
    }
}

// sum 4 split-K partial planes -> out
__global__ __launch_bounds__(256)
void splitk_reduce4(const float* __restrict__ P, float* __restrict__ out, int n) {
  const int i = (blockIdx.x * 256 + threadIdx.x) * 4;
  if (i >= n) return;
  float4 s = *reinterpret_cast<const float4*>(P + i);
  #pragma unroll
  for (int z = 1; z < 4; ++z) {
    const float4 v = *reinterpret_cast<const float4*>(P + (size_t)z * n + i);
    s.x += v.x; s.y += v.y; s.z += v.z; s.w += v.w;
  }
  *reinterpret_cast<float4*>(out + i) = s;
}

// ---------------------------------------------------------------------------
// Split-K f32 NT GEMM partials (x_proj)
// ---------------------------------------------------------------------------
template<int BM, int BN, int TM, int TN, int KSLICE>
__global__ __launch_bounds__(256)
void gemm_nt_part(const float* __restrict__ A, const float* __restrict__ Bw,
                  float* __restrict__ P, int M, int N, int lda, int ldb) {
  constexpr int BK  = 16;
  constexpr int NTX = BN / TN;
  constexpr int NTY = BM / TM;
  static_assert(NTX * NTY == 256, "thread tile mismatch");
  __shared__ float As[BK][BM + 4];
  __shared__ float Bs[BK][BN + 4];

  const int tid = threadIdx.x;
  const int m0  = blockIdx.y * BM;
  const int n0  = blockIdx.x * BN;
  const int kb  = blockIdx.z * KSLICE;
  const int tx  = tid % NTX;
  const int ty  = tid / NTX;

  float acc[TM][TN] = {};

  for (int k0 = kb; k0 < kb + KSLICE; k0 += BK) {
    __syncthreads();
    for (int t = tid; t < BM * 4; t += 256) {
      const int row = t >> 2, kq = t & 3;
      const float4 v = *reinterpret_cast<const float4*>(
          A + (size_t)(m0 + row) * lda + k0 + kq * 4);
      As[kq * 4 + 0][row] = v.x;
      As[kq * 4 + 1][row] = v.y;
      As[kq * 4 + 2][row] = v.z;
      As[kq * 4 + 3][row] = v.w;
    }
    for (int t = tid; t < BN * 4; t += 256) {
      const int row = t >> 2, kq = t & 3;
      const float4 v = *reinterpret_cast<const float4*>(
          Bw + (size_t)(n0 + row) * ldb + k0 + kq * 4);
      Bs[kq * 4 + 0][row] = v.x;
      Bs[kq * 4 + 1][row] = v.y;
      Bs[kq * 4 + 2][row] = v.z;
      Bs[kq * 4 + 3][row] = v.w;
    }
    __syncthreads();
    #pragma unroll
    for (int k = 0; k < BK; ++k) {
      float a[TM], b[TN];
      #pragma unroll
      for (int i = 0; i < TM; ++i) a[i] = As[k][ty * TM + i];
      #pragma unroll
      for (int j = 0; j < TN; ++j) b[j] = Bs[k][tx * TN + j];
      #pragma unroll
      for (int i = 0; i < TM; ++i)
        #pragma unroll
        for (int j = 0; j < TN; ++j)
          acc[i][j] = fmaf(a[i], b[j], acc[i][j]);
    }
  }

  float* out = P + (size_t)blockIdx.z * M * N;
  #pragma unroll
  for (int i = 0; i < TM; ++i)
    #pragma unroll
    for (int j = 0; j < TN; ++j)
      out[(size_t)(m0 + ty * TM + i) * N + n0 + tx * TN + j] = acc[i][j];
}

// reduce x_proj partials; dt cols (0..63) -> packed bf16 hi/lo, B/C cols -> f32
__global__ __launch_bounds__(256)
void xpr_fused(const float* __restrict__ part, float* __restrict__ xdbl,
               ushort* __restrict__ dth, ushort* __restrict__ dtl) {
  const int i = blockIdx.x * 256 + threadIdx.x;   // float4 over [2048][24]
  if (i >= MM * 24) return;
  const int m  = i / 24;
  const int c4 = (i % 24) * 4;
  const size_t off = (size_t)m * 96 + c4;
  float4 s = *reinterpret_cast<const float4*>(part + off);
  #pragma unroll
  for (int z = 1; z < 8; ++z) {
    const float4 v = *reinterpret_cast<const float4*>(part + (size_t)z * MM * 96 + off);
    s.x += v.x; s.y += v.y; s.z += v.z; s.w += v.w;
  }
  if (c4 < 64) {
    ushort4 h, l;
    h.x = bf16_rne(s.x); l.x = bf16_rne(s.x - __uint_as_float((uint)h.x << 16));
    h.y = bf16_rne(s.y); l.y = bf16_rne(s.y - __uint_as_float((uint)h.y << 16));
    h.z = bf16_rne(s.z); l.z = bf16_rne(s.z - __uint_as_float((uint)h.z << 16));
    h.w = bf16_rne(s.w); l.w = bf16_rne(s.w - __uint_as_float((uint)h.w << 16));
    *reinterpret_cast<ushort4*>(dth + (size_t)m * 64 + c4) = h;
    *reinterpret_cast<ushort4*>(dtl + (size_t)m * 64 + c4) = l;
  } else {
    *reinterpret_cast<float4*>(xdbl + off) = s;
  }
}

// ---------------------------------------------------------------------------
// Depthwise causal conv1d (k=4) + bias + SiLU, float4-vectorized.
// ---------------------------------------------------------------------------
__global__ __launch_bounds__(256)
void conv_silu(const float* __restrict__ xz, const float* __restrict__ cw,
               const float* __restrict__ cb, float* __restrict__ xc) {
  const int idx = blockIdx.x * 256 + threadIdx.x;   // over MM*DINNER/4
  if (idx >= MM * DINNER / 4) return;
  const int d4 = (idx & 511) * 4;       // DINNER/4 = 512 per row
  const int m  = idx >> 9;
  const int l  = m & (LL - 1);
  const int b  = m >> 10;

  float4 w0 = *reinterpret_cast<const float4*>(cw + (size_t)(d4 + 0) * 4);
  float4 w1 = *reinterpret_cast<const float4*>(cw + (size_t)(d4 + 1) * 4);
  float4 w2 = *reinterpret_cast<const float4*>(cw + (size_t)(d4 + 2) * 4);
  float4 w3 = *reinterpret_cast<const float4*>(cw + (size_t)(d4 + 3) * 4);
  float4 acc = *reinterpret_cast<const float4*>(cb + d4);

  #pragma unroll
  for (int j = 0; j < DCONV; ++j) {
    const int ll = l - (DCONV - 1) + j;
    if (ll >= 0) {
      const float4 xv = *reinterpret_cast<const float4*>(
          xz + ((size_t)(b * LL + ll) << 12) + d4);
      acc.x = fmaf(xv.x, (&w0.x)[j], acc.x);
      acc.y = fmaf(xv.y, (&w1.x)[j], acc.y);
      acc.z = fmaf(xv.z, (&w2.x)[j], acc.z);
      acc.w = fmaf(xv.w, (&w3.x)[j], acc.w);
    }
  }
  float4 o;
  o.x = acc.x / (1.f + __expf(-acc.x));
  o.y = acc.y / (1.f + __expf(-acc.y));
  o.z = acc.z / (1.f + __expf(-acc.z));
  o.w = acc.w / (1.f + __expf(-acc.w));
  *reinterpret_cast<float4*>(xc + (size_t)m * DINNER + d4) = o;
}

// ---------------------------------------------------------------------------
// Chunked parallel selective scan (3 passes).
// ---------------------------------------------------------------------------
__device__ __forceinline__ void stage_tile(const float* g, int stride,
                                           float* ldst, int lane) {
  const int r  = lane >> 2;
  const int q4 = (lane & 3) * 4;
  #pragma unroll
  for (int i = 0; i < 4; ++i) {
    __builtin_amdgcn_global_load_lds(
        AS1(g + (size_t)(i * 16 + r) * stride + q4),
        AS3(ldst + i * 256), 16, 0, 0);
  }
}

__device__ __forceinline__ float quad_sum(float v) {
  int i = __float_as_int(v);
  v += __int_as_float(__builtin_amdgcn_update_dpp(0, i, 0xB1, 0xf, 0xf, true)); // xor 1
  i = __float_as_int(v);
  v += __int_as_float(__builtin_amdgcn_update_dpp(0, i, 0x4E, 0xf, 0xf, true)); // xor 2
  return v;
}

__global__ __launch_bounds__(64)
void scan_chunk_state(const float* __restrict__ delta, const float* __restrict__ xc,
                      const float* __restrict__ xdbl, const float* __restrict__ A_log,
                      float* __restrict__ hend, float* __restrict__ aprod) {
  __shared__ float dT[CL][16];
  __shared__ float xT[CL][16];
  __shared__ float bT[CL][16];

  const int idx = blockIdx.x;          // (b*128 + dg)*16 + c
  const int c  = idx & 15;
  const int dg = (idx >> 4) & 127;
  const int b  = idx >> 11;
  const int t  = threadIdx.x;
  const int ch = t >> 2;
  const int q  = t & 3;
  const int d  = dg * 16 + ch;

  const size_t r0 = (size_t)b * LL + (size_t)c * CL;
  stage_tile(delta + r0 * DINNER + dg * 16, DINNER, &dT[0][0], t);
  stage_tile(xc    + r0 * DINNER + dg * 16, DINNER, &xT[0][0], t);
  stage_tile(xdbl  + r0 * 96 + DTRANK,          96, &bT[0][0], t);

  float Adn[4];
  #pragma unroll
  for (int j = 0; j < 4; ++j)
    Adn[j] = -__expf(A_log[d * DSTATE + 4 * q + j]);
  float h0 = 0.f, h1 = 0.f, h2 = 0.f, h3 = 0.f;
  float p0 = 1.f, p1 = 1.f, p2 = 1.f, p3 = 1.f;

  __syncthreads();

  #pragma unroll 8
  for (int l = 0; l < CL; ++l) {
    const float dv = dT[l][ch];
    const float xv = xT[l][ch];
    const float4 B4 = *reinterpret_cast<const float4*>(&bT[l][4 * q]);
    const float dvx = dv * xv;
    const float a0 = __expf(dv * Adn[0]);
    const float a1 = __expf(dv * Adn[1]);
    const float a2 = __expf(dv * Adn[2]);
    const float a3 = __expf(dv * Adn[3]);
    h0 = fmaf(a0, h0, dvx * B4.x);  p0 *= a0;
    h1 = fmaf(a1, h1, dvx * B4.y);  p1 *= a1;
    h2 = fmaf(a2, h2, dvx * B4.z);  p2 *= a2;
    h3 = fmaf(a3, h3, dvx * B4.w);  p3 *= a3;
  }

  const size_t base = (((size_t)(b * NCH + c) * DINNER) + d) * DSTATE + 4 * q;
  *reinterpret_cast<float4*>(hend  + base) = (float4){h0, h1, h2, h3};
  *reinterpret_cast<float4*>(aprod + base) = (float4){p0, p1, p2, p3};
}

__global__ __launch_bounds__(256)
void scan_combine(const float* __restrict__ hend, const float* __restrict__ aprod,
                  float* __restrict__ hin) {
  const int tid = blockIdx.x * 256 + threadIdx.x;   // 65536 total
  const size_t cstride = (size_t)DINNER * DSTATE;   // 32768
  const size_t base = (size_t)(tid >> 15) * NCH * cstride + (tid & 32767);
  float h = 0.f;
  hin[base] = 0.f;
  #pragma unroll
  for (int c = 0; c < NCH - 1; ++c) {
    h = fmaf(aprod[base + (size_t)c * cstride], h, hend[base + (size_t)c * cstride]);
    hin[base + (size_t)(c + 1) * cstride] = h;
  }
}

__global__ __launch_bounds__(64)
void scan_apply(const float* __restrict__ delta, const float* __restrict__ xc,
                const float* __restrict__ xdbl, const float* __restrict__ xz,
                const float* __restrict__ A_log, const float* __restrict__ Dp,
                const float* __restrict__ hin, ushort* __restrict__ yh) {
  __shared__ float dT[CL][16];
  __shared__ float xT[CL][16];
  __shared__ float bT[CL][16];
  __shared__ float cT[CL][16];
  __shared__ float zT[CL][16];

  const int idx = blockIdx.x;
  const int c  = idx & 15;
  const int dg = (idx >> 4) & 127;
  const int b  = idx >> 11;
  const int t  = threadIdx.x;
  const int ch = t >> 2;
  const int q  = t & 3;
  const int d  = dg * 16 + ch;

  const size_t r0 = (size_t)b * LL + (size_t)c * CL;
  stage_tile(delta + r0 * DINNER + dg * 16, DINNER, &dT[0][0], t);
  stage_tile(xc    + r0 * DINNER + dg * 16, DINNER, &xT[0][0], t);
  stage_tile(xdbl  + r0 * 96 + DTRANK,          96, &bT[0][0], t);
  stage_tile(xdbl  + r0 * 96 + DTRANK + DSTATE, 96, &cT[0][0], t);
  stage_tile(xz    + (r0 << 12) + DINNER + dg * 16, 4096, &zT[0][0], t);

  float Adn[4];
  #pragma unroll
  for (int j = 0; j < 4; ++j)
    Adn[j] = -__expf(A_log[d * DSTATE + 4 * q + j]);
  const float Dd = Dp[d];

  const size_t base = (((size_t)(b * NCH + c) * DINNER) + d) * DSTATE + 4 * q;
  const float4 h4 = *reinterpret_cast<const float4*>(hin + base);
  float h0 = h4.x, h1 = h4.y, h2 = h4.z, h3 = h4.w;

  __syncthreads();

  #pragma unroll 8
  for (int l = 0; l < CL; ++l) {
    const float dv = dT[l][ch];
    const float xv = xT[l][ch];
    const float4 B4 = *reinterpret_cast<const float4*>(&bT[l][4 * q]);
    const float4 C4 = *reinterpret_cast<const float4*>(&cT[l][4 * q]);
    const float dvx = dv * xv;
    const float a0 = __expf(dv * Adn[0]);
    const float a1 = __expf(dv * Adn[1]);
    const float a2 = __expf(dv * Adn[2]);
    const float a3 = __expf(dv * Adn[3]);
    h0 = fmaf(a0, h0, dvx * B4.x);
    h1 = fmaf(a1, h1, dvx * B4.y);
    h2 = fmaf(a2, h2, dvx * B4.z);
    h3 = fmaf(a3, h3, dvx * B4.w);
    float ys = fmaf(h0, C4.x, fmaf(h1, C4.y, fmaf(h2, C4.z, h3 * C4.w)));
    ys = quad_sum(ys);
    if (q == 0) {
      const float g = zT[l][ch];        // silu(z) precomputed by in_proj epilogue
      const float tv = (ys + xv * Dd) * g;
      yh[(r0 + l) * (size_t)DINNER + d] = bf16_rne(tv);
    }
  }
}

// ---------------------------------------------------------------------------
extern "C" void kernel_launch(void* const* d_in, const int* in_sizes, int n_in,
                              void* d_out, int out_size, void* d_ws, size_t ws_size,
                              hipStream_t stream) {
  const float* x         = (const float*)d_in[0];
  const float* in_proj_w = (const float*)d_in[1];
  const float* conv_w    = (const float*)d_in[2];
  const float* conv_b    = (const float*)d_in[3];
  const float* x_proj_w  = (const float*)d_in[4];
  const float* dt_proj_w = (const float*)d_in[5];
  const float* dt_proj_b = (const float*)d_in[6];
  const float* A_log     = (const float*)d_in[7];
  const float* Dv        = (const float*)d_in[8];
  const float* out_proj_w= (const float*)d_in[9];
  float* out = (float*)d_out;

  float* ws    = (float*)d_ws;
  float* xz    = ws;                          // [2048][4096] f32
  float* xc    = xz    + (size_t)MM * 4096;   // [2048][2048] f32
  float* xdbl  = xc    + (size_t)MM * DINNER; // [2048][96]   f32
  float* delta = xdbl  + (size_t)MM * 96;     // [2048][2048] f32
  ushort* us   = (ushort*)(delta + (size_t)MM * DINNER);
  ushort* yhp  = us;                           // [2048][2048] bf16 hi
  ushort* ylp  = yhp + (size_t)MM * DINNER;    // repurposed: dt/wd planes
  ushort* xh   = ylp + (size_t)MM * DINNER;    // [2048][1024]
  ushort* xl   = xh  + (size_t)MM * DMODEL;    // (unused)
  ushort* wih  = xl  + (size_t)MM * DMODEL;    // [4096][1024]
  ushort* wil  = wih + (size_t)4096 * DMODEL;  // (unused now)
  ushort* woh  = wil + (size_t)4096 * DMODEL;  // [1024][2048]

  // dt hi/lo + dt_proj_w hi/lo live in the old yl region (never else used)
  ushort* dth = ylp;
  ushort* dtl = ylp + 131072;
  ushort* wdh = ylp + 262144;
  ushort* wdl = ylp + 393216;

  // hend/aprod/hin (scan) live in wil region (never written now; wih dead
  // after in_proj GEMM, but use wil to be safe -- 8.4 MB gives room for
  // 3 x 4.2 MB? No: keep them in wih as before, dead after in_proj.)
  float* hend  = (float*)wih;
  float* aprod = hend  + (size_t)BB * NCH * DINNER * DSTATE;
  float* hin   = aprod + (size_t)BB * NCH * DINNER * DSTATE;
  // x_proj split-K partials [8][2048][96] = 6.3 MB (consumed before scan)
  float* part  = hend;
  // out_proj split-K partials [4][2048][1024] f32 = 33.55 MB: the xz region
  // (dead after scan_apply reads the z half)
  float* opart = xz;

  const dim3 blk(256);

  // 0) fused precision splits (x hi, in_proj_w hi, out_proj_w hi, dt_proj_w hi+lo)
  {
    const int n0 = (MM * DMODEL) / 4, n1 = (4096 * DMODEL) / 4,
              n2 = (DMODEL * DINNER) / 4, n3 = (DINNER * DTRANK) / 4;
    split3<<<dim3((n0 + n1 + n2 + n3) / 256), blk, 0, stream>>>(
        x, xh, nullptr, n0, in_proj_w, wih, nullptr, n1,
        out_proj_w, woh, nullptr, n2, dt_proj_w, wdh, wdl, n3);
  }

  // 1) in_proj (1-product bf16 MFMA + fused z-gate silu): xz = x @ in_proj_w^T
  gemm_p1_mfma<2,1><<<dim3(4096 / 128, MM / 128), blk, 0, stream>>>(
      xh, wih, xz, MM, 4096, DMODEL);

  // 2) causal depthwise conv + silu -> xc
  conv_silu<<<dim3((MM * DINNER / 4) / 256), blk, 0, stream>>>(xz, conv_w, conv_b, xc);

  // 3) x_proj split-K + fused reduce/dt-split
  gemm_nt_part<64,32,4,2,256><<<dim3(96/32, MM/64, 8), blk, 0, stream>>>(
      xc, x_proj_w, part, MM, 96, DINNER, DINNER);
  xpr_fused<<<dim3((MM * 24 + 255) / 256), blk, 0, stream>>>(part, xdbl, dth, dtl);

  // 4) dt_proj (MFMA split-bf16 3-product + softplus)
  gemm_hl_mfma<1,1><<<dim3(DINNER / 128, MM / 128), blk, 0, stream>>>(
      dth, dtl, wdh, wdl, delta, dt_proj_b, MM, DINNER, DTRANK);

  // 5) chunked parallel scan
  scan_chunk_state<<<dim3(BB * 128 * NCH), dim3(64), 0, stream>>>(
      delta, xc, xdbl, A_log, hend, aprod);
  scan_combine<<<dim3(BB * DINNER * DSTATE / 256), blk, 0, stream>>>(
      hend, aprod, hin);
  scan_apply<<<dim3(BB * 128 * NCH), dim3(64), 0, stream>>>(
      delta, xc, xdbl, xz, A_log, Dv, hin, yhp);

  // 6) out_proj (1-product bf16 MFMA, split-K=4): out = y @ out_proj_w^T
  gemm_p1_mfma<0,4><<<dim3(DMODEL / 128, MM / 128, 4), blk, 0, stream>>>(
      yhp, woh, opart, MM, DMODEL, DINNER);
  splitk_reduce4<<<dim3((MM * DMODEL) / 1024), blk, 0, stream>>>(
      opart, out, MM * DMODEL);
}

// Round 13
// 167.446 us; speedup vs baseline: 1.1862x; 1.0000x over previous
//
#include <hip/hip_runtime.h>
#include <math.h>
#include <stdint.h>

#define DMODEL 1024
#define DINNER 2048
#define DCONV  4
#define DSTATE 16
#define DTRANK 64
#define BB 2
#define LL 1024
#define MM (BB * LL)            // 2048 rows in all GEMMs

#define CL  64                  // scan chunk length
#define NCH (LL / CL)           // 16 chunks

#define AS1(p) ((__attribute__((address_space(1))) void*)(void*)(p))
#define AS3(p) ((__attribute__((address_space(3))) void*)(void*)(p))

typedef __attribute__((ext_vector_type(8))) short bf16x8;
typedef __attribute__((ext_vector_type(4))) float f32x4;

__device__ __forceinline__ ushort bf16_rne(float f) {
  uint32_t u = __float_as_uint(f);
  uint32_t r = (u + 0x7fffu + ((u >> 16) & 1u)) >> 16;
  return (ushort)r;
}
__device__ __forceinline__ float bf2f(ushort u) {
  return __uint_as_float((uint32_t)u << 16);
}

// ---------------------------------------------------------------------------
// Fused f32 -> (hi[, lo]) bf16 split for 4 arrays in one launch.
// ---------------------------------------------------------------------------
__device__ __forceinline__ void split4(const float* __restrict__ in,
                                       ushort* __restrict__ hi,
                                       ushort* __restrict__ lo, int i4) {
  const float4 v = *reinterpret_cast<const float4*>(in + (size_t)i4 * 4);
  ushort4 h;
  h.x = bf16_rne(v.x); h.y = bf16_rne(v.y);
  h.z = bf16_rne(v.z); h.w = bf16_rne(v.w);
  *reinterpret_cast<ushort4*>(hi + (size_t)i4 * 4) = h;
  if (lo) {
    ushort4 l;
    l.x = bf16_rne(v.x - bf2f(h.x));
    l.y = bf16_rne(v.y - bf2f(h.y));
    l.z = bf16_rne(v.z - bf2f(h.z));
    l.w = bf16_rne(v.w - bf2f(h.w));
    *reinterpret_cast<ushort4*>(lo + (size_t)i4 * 4) = l;
  }
}

__global__ __launch_bounds__(256)
void split3(const float* s0, ushort* h0, ushort* l0, int n0,
            const float* s1, ushort* h1, ushort* l1, int n1,
            const float* s2, ushort* h2, ushort* l2, int n2,
            const float* s3, ushort* h3, ushort* l3, int n3) {
  int i = blockIdx.x * 256 + threadIdx.x;
  if (i < n0) { split4(s0, h0, l0, i); return; }
  i -= n0;
  if (i < n1) { split4(s1, h1, l1, i); return; }
  i -= n1;
  if (i < n2) { split4(s2, h2, l2, i); return; }
  i -= n2;
  if (i < n3) { split4(s3, h3, l3, i); return; }
}

__device__ __forceinline__ int swz4(int r) { return (r & 3) ^ ((r >> 2) & 3); }

// ---------------------------------------------------------------------------
// Split-precision bf16 MFMA NT GEMM (3-product), 2-phase double-buffered.
// Used only for dt_proj.  EPI 1: softplus(acc+bias).
// ---------------------------------------------------------------------------
template<int EPI, int SPLITK>
__global__ __launch_bounds__(256)
void gemm_hl_mfma(const ushort* __restrict__ Ahg, const ushort* __restrict__ Alg,
                  const ushort* __restrict__ Bhg, const ushort* __restrict__ Blg,
                  float* __restrict__ C, const float* __restrict__ bias,
                  int M, int N, int K) {
  __shared__ ushort Ah[2][128][32];
  __shared__ ushort Al[2][128][32];
  __shared__ ushort Bh[2][128][32];
  __shared__ ushort Bl[2][128][32];

  const int tid  = threadIdx.x;
  const int wave = tid >> 6;
  const int lane = tid & 63;
  const int m0 = blockIdx.y * 128;
  const int n0 = blockIdx.x * 128;
  const int wm = (wave >> 1) * 64;
  const int wn = (wave & 1) * 64;

  const int ksl = K / SPLITK;
  const int kb  = blockIdx.z * ksl;
  float* Cout   = C + (size_t)blockIdx.z * M * N;

  f32x4 acc[4][4];
  #pragma unroll
  for (int i = 0; i < 4; ++i)
    #pragma unroll
    for (int j = 0; j < 4; ++j)
      acc[i][j] = (f32x4){0.f, 0.f, 0.f, 0.f};

  const ushort* gsrc; ushort* dst; int row0;
  if      (wave == 0) { gsrc = Ahg; dst = &Ah[0][0][0]; row0 = m0; }
  else if (wave == 1) { gsrc = Alg; dst = &Al[0][0][0]; row0 = m0; }
  else if (wave == 2) { gsrc = Bhg; dst = &Bh[0][0][0]; row0 = n0; }
  else                { gsrc = Blg; dst = &Bl[0][0][0]; row0 = n0; }

  const int lr = lane >> 2;
  const int ls = lane & 3;
  const int fr = lane & 15;
  const int q  = lane >> 4;

  auto STAGE = [&](int bi, int k0) {
    ushort* d = dst + bi * 4096;
    #pragma unroll
    for (int seg = 0; seg < 8; ++seg) {
      const int rho = seg * 16 + lr;
      const int ks  = (ls ^ swz4(rho)) * 8;
      __builtin_amdgcn_global_load_lds(
          AS1(gsrc + (size_t)(row0 + rho) * K + k0 + ks),
          AS3(d + seg * 512), 16, 0, 0);
    }
  };

  const int NT = ksl / 32;
  STAGE(0, kb);
  __syncthreads();

  int cur = 0;
  for (int kt = 0; kt < NT; ++kt) {
    if (kt + 1 < NT) STAGE(cur ^ 1, kb + (kt + 1) * 32);

    bf16x8 ah[4], al[4], bh[4], bl[4];
    #pragma unroll
    for (int f = 0; f < 4; ++f) {
      { const int r = wm + f * 16 + fr; const int s = 8 * (q ^ swz4(r));
        ah[f] = *reinterpret_cast<const bf16x8*>(&Ah[cur][r][s]);
        al[f] = *reinterpret_cast<const bf16x8*>(&Al[cur][r][s]); }
      { const int r = wn + f * 16 + fr; const int s = 8 * (q ^ swz4(r));
        bh[f] = *reinterpret_cast<const bf16x8*>(&Bh[cur][r][s]);
        bl[f] = *reinterpret_cast<const bf16x8*>(&Bl[cur][r][s]); }
    }
    #pragma unroll
    for (int i = 0; i < 4; ++i)
      #pragma unroll
      for (int j = 0; j < 4; ++j) {
        acc[i][j] = __builtin_amdgcn_mfma_f32_16x16x32_bf16(ah[i], bh[j], acc[i][j], 0, 0, 0);
        acc[i][j] = __builtin_amdgcn_mfma_f32_16x16x32_bf16(al[i], bh[j], acc[i][j], 0, 0, 0);
        acc[i][j] = __builtin_amdgcn_mfma_f32_16x16x32_bf16(ah[i], bl[j], acc[i][j], 0, 0, 0);
      }

    __syncthreads();
    cur ^= 1;
  }

  const int cr = (lane >> 4) * 4;
  const int cc = lane & 15;
  #pragma unroll
  for (int i = 0; i < 4; ++i)
    #pragma unroll
    for (int j = 0; j < 4; ++j) {
      const int cn = n0 + wn + j * 16 + cc;
      const float bj = (EPI == 1) ? bias[cn] : 0.f;
      const size_t base = (size_t)(m0 + wm + i * 16 + cr) * N + cn;
      #pragma unroll
      for (int r = 0; r < 4; ++r) {
        float v = acc[i][j][r];
        if (EPI == 1) {
          v += bj;
          v = fmaxf(v, 0.f) + __logf(1.f + __expf(-fabsf(v)));   // softplus
        }
        Cout[base + (size_t)r * N] = v;
      }
    }
}

// ---------------------------------------------------------------------------
// 1-product MFMA NT GEMM with LDS-coalesced epilogue.
// C = Ah @ Bh^T, 2 staged planes, 32 KB LDS (one buffer, aliased for the
// epilogue), 2-phase double-buffered, SPLITK via blockIdx.z.
// EPI 0: plain.  EPI 2: silu for column-blocks n0 >= DINNER (z-gate).
// OBF16: store bf16 (Pb); else f32 (Pf).
// Epilogue: each wave round-trips its 64x64 acc tile through its private
// 8 KB LDS slice (2 passes of 32x64), then stores full cache lines.
// ---------------------------------------------------------------------------
template<int EPI, int SPLITK, bool OBF16>
__global__ __launch_bounds__(256)
void gemm_p1_mfma(const ushort* __restrict__ Ahg, const ushort* __restrict__ Bhg,
                  float* __restrict__ Pf, ushort* __restrict__ Pb,
                  int M, int N, int K) {
  __shared__ ushort smem[16384];     // 32 KB: A planes [0,8192), B [8192,16384)

  const int tid  = threadIdx.x;
  const int wave = tid >> 6;
  const int lane = tid & 63;
  const int m0 = blockIdx.y * 128;
  const int n0 = blockIdx.x * 128;
  const int wm = (wave >> 1) * 64;
  const int wn = (wave & 1) * 64;

  const int ksl = K / SPLITK;
  const int kb  = blockIdx.z * ksl;

  f32x4 acc[4][4];
  #pragma unroll
  for (int i = 0; i < 4; ++i)
    #pragma unroll
    for (int j = 0; j < 4; ++j)
      acc[i][j] = (f32x4){0.f, 0.f, 0.f, 0.f};

  const ushort* gsrc = nullptr; ushort* dst = nullptr; int row0 = 0;
  if      (wave == 0) { gsrc = Ahg; dst = smem;        row0 = m0; }
  else if (wave == 1) { gsrc = Bhg; dst = smem + 8192; row0 = n0; }

  const int lr = lane >> 2;
  const int ls = lane & 3;
  const int fr = lane & 15;
  const int q  = lane >> 4;

  auto STAGE = [&](int bi, int k0) {
    if (wave >= 2) return;
    ushort* d = dst + bi * 4096;
    #pragma unroll
    for (int seg = 0; seg < 8; ++seg) {
      const int rho = seg * 16 + lr;
      const int ks  = (ls ^ swz4(rho)) * 8;
      __builtin_amdgcn_global_load_lds(
          AS1(gsrc + (size_t)(row0 + rho) * K + k0 + ks),
          AS3(d + seg * 512), 16, 0, 0);
    }
  };

  const int NT = ksl / 32;
  STAGE(0, kb);
  __syncthreads();

  int cur = 0;
  for (int kt = 0; kt < NT; ++kt) {
    if (kt + 1 < NT) STAGE(cur ^ 1, kb + (kt + 1) * 32);

    bf16x8 ah[4], bh[4];
    #pragma unroll
    for (int f = 0; f < 4; ++f) {
      { const int r = wm + f * 16 + fr; const int s = 8 * (q ^ swz4(r));
        ah[f] = *reinterpret_cast<const bf16x8*>(&smem[cur * 4096 + r * 32 + s]); }
      { const int r = wn + f * 16 + fr; const int s = 8 * (q ^ swz4(r));
        bh[f] = *reinterpret_cast<const bf16x8*>(&smem[8192 + cur * 4096 + r * 32 + s]); }
    }
    #pragma unroll
    for (int i = 0; i < 4; ++i)
      #pragma unroll
      for (int j = 0; j < 4; ++j)
        acc[i][j] = __builtin_amdgcn_mfma_f32_16x16x32_bf16(ah[i], bh[j], acc[i][j], 0, 0, 0);

    __syncthreads();
    cur ^= 1;
  }
  // loop ends with a barrier -> LDS is free; each wave uses its own 8 KB slice.

  float* T = reinterpret_cast<float*>(smem) + wave * 2048;   // [32][64]
  const int cr = (lane >> 4) * 4;
  const int cc = lane & 15;
  const bool do_silu = (EPI == 2) && (n0 >= DINNER);

  #pragma unroll
  for (int p = 0; p < 2; ++p) {
    #pragma unroll
    for (int ii = 0; ii < 2; ++ii) {
      const int i = 2 * p + ii;
      #pragma unroll
      for (int j = 0; j < 4; ++j)
        #pragma unroll
        for (int r = 0; r < 4; ++r)
          T[(ii * 16 + cr + r) * 64 + j * 16 + cc] = acc[i][j][r];
    }
    // same-wave ds_write -> ds_read: lgkmcnt ordering handled by compiler
    #pragma unroll
    for (int rr = 0; rr < 8; ++rr) {
      const int row  = rr * 4 + (lane >> 4);     // 0..31
      const int col4 = (lane & 15) * 4;
      float4 v = *reinterpret_cast<const float4*>(&T[row * 64 + col4]);
      const size_t grow = (size_t)(m0 + wm + p * 32 + row);
      const int    gcol = n0 + wn + col4;
      if (do_silu) {
        v.x = v.x / (1.f + __expf(-v.x));
        v.y = v.y / (1.f + __expf(-v.y));
        v.z = v.z / (1.f + __expf(-v.z));
        v.w = v.w / (1.f + __expf(-v.w));
      }
      if (OBF16) {
        ushort4 h;
        h.x = bf16_rne(v.x); h.y = bf16_rne(v.y);
        h.z = bf16_rne(v.z); h.w = bf16_rne(v.w);
        *reinterpret_cast<ushort4*>(Pb + grow * N + gcol) = h;
      } else {
        float* Cout = Pf + (size_t)blockIdx.z * M * N;
        *reinterpret_cast<float4*>(Cout + grow * N + gcol) = v;
      }
    }
  }
}

// sum 4 split-K partial planes -> out
__global__ __launch_bounds__(256)
void splitk_reduce4(const float* __restrict__ P, float* __restrict__ out, int n) {
  const int i = (blockIdx.x * 256 + threadIdx.x) * 4;
  if (i >= n) return;
  float4 s = *reinterpret_cast<const float4*>(P + i);
  #pragma unroll
  for (int z = 1; z < 4; ++z) {
    const float4 v = *reinterpret_cast<const float4*>(P + (size_t)z * n + i);
    s.x += v.x; s.y += v.y; s.z += v.z; s.w += v.w;
  }
  *reinterpret_cast<float4*>(out + i) = s;
}

// ---------------------------------------------------------------------------
// Split-K f32 NT GEMM partials (x_proj)
// ---------------------------------------------------------------------------
template<int BM, int BN, int TM, int TN, int KSLICE>
__global__ __launch_bounds__(256)
void gemm_nt_part(const float* __restrict__ A, const float* __restrict__ Bw,
                  float* __restrict__ P, int M, int N, int lda, int ldb) {
  constexpr int BK  = 16;
  constexpr int NTX = BN / TN;
  constexpr int NTY = BM / TM;
  static_assert(NTX * NTY == 256, "thread tile mismatch");
  __shared__ float As[BK][BM + 4];
  __shared__ float Bs[BK][BN + 4];

  const int tid = threadIdx.x;
  const int m0  = blockIdx.y * BM;
  const int n0  = blockIdx.x * BN;
  const int kb  = blockIdx.z * KSLICE;
  const int tx  = tid % NTX;
  const int ty  = tid / NTX;

  float acc[TM][TN] = {};

  for (int k0 = kb; k0 < kb + KSLICE; k0 += BK) {
    __syncthreads();
    for (int t = tid; t < BM * 4; t += 256) {
      const int row = t >> 2, kq = t & 3;
      const float4 v = *reinterpret_cast<const float4*>(
          A + (size_t)(m0 + row) * lda + k0 + kq * 4);
      As[kq * 4 + 0][row] = v.x;
      As[kq * 4 + 1][row] = v.y;
      As[kq * 4 + 2][row] = v.z;
      As[kq * 4 + 3][row] = v.w;
    }
    for (int t = tid; t < BN * 4; t += 256) {
      const int row = t >> 2, kq = t & 3;
      const float4 v = *reinterpret_cast<const float4*>(
          Bw + (size_t)(n0 + row) * ldb + k0 + kq * 4);
      Bs[kq * 4 + 0][row] = v.x;
      Bs[kq * 4 + 1][row] = v.y;
      Bs[kq * 4 + 2][row] = v.z;
      Bs[kq * 4 + 3][row] = v.w;
    }
    __syncthreads();
    #pragma unroll
    for (int k = 0; k < BK; ++k) {
      float a[TM], b[TN];
      #pragma unroll
      for (int i = 0; i < TM; ++i) a[i] = As[k][ty * TM + i];
      #pragma unroll
      for (int j = 0; j < TN; ++j) b[j] = Bs[k][tx * TN + j];
      #pragma unroll
      for (int i = 0; i < TM; ++i)
        #pragma unroll
        for (int j = 0; j < TN; ++j)
          acc[i][j] = fmaf(a[i], b[j], acc[i][j]);
    }
  }

  float* out = P + (size_t)blockIdx.z * M * N;
  #pragma unroll
  for (int i = 0; i < TM; ++i)
    #pragma unroll
    for (int j = 0; j < TN; ++j)
      out[(size_t)(m0 + ty * TM + i) * N + n0 + tx * TN + j] = acc[i][j];
}

// reduce x_proj partials; dt cols (0..63) -> packed bf16 hi/lo, B/C cols -> f32
__global__ __launch_bounds__(256)
void xpr_fused(const float* __restrict__ part, float* __restrict__ xdbl,
               ushort* __restrict__ dth, ushort* __restrict__ dtl) {
  const int i = blockIdx.x * 256 + threadIdx.x;   // float4 over [2048][24]
  if (i >= MM * 24) return;
  const int m  = i / 24;
  const int c4 = (i % 24) * 4;
  const size_t off = (size_t)m * 96 + c4;
  float4 s = *reinterpret_cast<const float4*>(part + off);
  #pragma unroll
  for (int z = 1; z < 8; ++z) {
    const float4 v = *reinterpret_cast<const float4*>(part + (size_t)z * MM * 96 + off);
    s.x += v.x; s.y += v.y; s.z += v.z; s.w += v.w;
  }
  if (c4 < 64) {
    ushort4 h, l;
    h.x = bf16_rne(s.x); l.x = bf16_rne(s.x - bf2f(h.x));
    h.y = bf16_rne(s.y); l.y = bf16_rne(s.y - bf2f(h.y));
    h.z = bf16_rne(s.z); l.z = bf16_rne(s.z - bf2f(h.z));
    h.w = bf16_rne(s.w); l.w = bf16_rne(s.w - bf2f(h.w));
    *reinterpret_cast<ushort4*>(dth + (size_t)m * 64 + c4) = h;
    *reinterpret_cast<ushort4*>(dtl + (size_t)m * 64 + c4) = l;
  } else {
    *reinterpret_cast<float4*>(xdbl + off) = s;
  }
}

// ---------------------------------------------------------------------------
// Depthwise causal conv1d (k=4) + bias + SiLU; reads bf16 xz, writes f32 xc.
// ---------------------------------------------------------------------------
__global__ __launch_bounds__(256)
void conv_silu(const ushort* __restrict__ xzb, const float* __restrict__ cw,
               const float* __restrict__ cb, float* __restrict__ xc) {
  const int idx = blockIdx.x * 256 + threadIdx.x;   // over MM*DINNER/4
  if (idx >= MM * DINNER / 4) return;
  const int d4 = (idx & 511) * 4;       // DINNER/4 = 512 per row
  const int m  = idx >> 9;
  const int l  = m & (LL - 1);
  const int b  = m >> 10;

  float4 w0 = *reinterpret_cast<const float4*>(cw + (size_t)(d4 + 0) * 4);
  float4 w1 = *reinterpret_cast<const float4*>(cw + (size_t)(d4 + 1) * 4);
  float4 w2 = *reinterpret_cast<const float4*>(cw + (size_t)(d4 + 2) * 4);
  float4 w3 = *reinterpret_cast<const float4*>(cw + (size_t)(d4 + 3) * 4);
  float4 acc = *reinterpret_cast<const float4*>(cb + d4);

  #pragma unroll
  for (int j = 0; j < DCONV; ++j) {
    const int ll = l - (DCONV - 1) + j;
    if (ll >= 0) {
      const ushort4 xv = *reinterpret_cast<const ushort4*>(
          xzb + ((size_t)(b * LL + ll) << 12) + d4);
      acc.x = fmaf(bf2f(xv.x), (&w0.x)[j], acc.x);
      acc.y = fmaf(bf2f(xv.y), (&w1.x)[j], acc.y);
      acc.z = fmaf(bf2f(xv.z), (&w2.x)[j], acc.z);
      acc.w = fmaf(bf2f(xv.w), (&w3.x)[j], acc.w);
    }
  }
  float4 o;
  o.x = acc.x / (1.f + __expf(-acc.x));
  o.y = acc.y / (1.f + __expf(-acc.y));
  o.z = acc.z / (1.f + __expf(-acc.z));
  o.w = acc.w / (1.f + __expf(-acc.w));
  *reinterpret_cast<float4*>(xc + (size_t)m * DINNER + d4) = o;
}

// ---------------------------------------------------------------------------
// Chunked parallel selective scan (3 passes).
// ---------------------------------------------------------------------------
__device__ __forceinline__ void stage_tile(const float* g, int stride,
                                           float* ldst, int lane) {
  const int r  = lane >> 2;
  const int q4 = (lane & 3) * 4;
  #pragma unroll
  for (int i = 0; i < 4; ++i) {
    __builtin_amdgcn_global_load_lds(
        AS1(g + (size_t)(i * 16 + r) * stride + q4),
        AS3(ldst + i * 256), 16, 0, 0);
  }
}

__device__ __forceinline__ float quad_sum(float v) {
  int i = __float_as_int(v);
  v += __int_as_float(__builtin_amdgcn_update_dpp(0, i, 0xB1, 0xf, 0xf, true)); // xor 1
  i = __float_as_int(v);
  v += __int_as_float(__builtin_amdgcn_update_dpp(0, i, 0x4E, 0xf, 0xf, true)); // xor 2
  return v;
}

__global__ __launch_bounds__(64)
void scan_chunk_state(const float* __restrict__ delta, const float* __restrict__ xc,
                      const float* __restrict__ xdbl, const float* __restrict__ A_log,
                      float* __restrict__ hend, float* __restrict__ aprod) {
  __shared__ float dT[CL][16];
  __shared__ float xT[CL][16];
  __shared__ float bT[CL][16];

  const int idx = blockIdx.x;          // (b*128 + dg)*16 + c
  const int c  = idx & 15;
  const int dg = (idx >> 4) & 127;
  const int b  = idx >> 11;
  const int t  = threadIdx.x;
  const int ch = t >> 2;
  const int q  = t & 3;
  const int d  = dg * 16 + ch;

  const size_t r0 = (size_t)b * LL + (size_t)c * CL;
  stage_tile(delta + r0 * DINNER + dg * 16, DINNER, &dT[0][0], t);
  stage_tile(xc    + r0 * DINNER + dg * 16, DINNER, &xT[0][0], t);
  stage_tile(xdbl  + r0 * 96 + DTRANK,          96, &bT[0][0], t);

  float Adn[4];
  #pragma unroll
  for (int j = 0; j < 4; ++j)
    Adn[j] = -__expf(A_log[d * DSTATE + 4 * q + j]);
  float h0 = 0.f, h1 = 0.f, h2 = 0.f, h3 = 0.f;
  float p0 = 1.f, p1 = 1.f, p2 = 1.f, p3 = 1.f;

  __syncthreads();

  #pragma unroll 8
  for (int l = 0; l < CL; ++l) {
    const float dv = dT[l][ch];
    const float xv = xT[l][ch];
    const float4 B4 = *reinterpret_cast<const float4*>(&bT[l][4 * q]);
    const float dvx = dv * xv;
    const float a0 = __expf(dv * Adn[0]);
    const float a1 = __expf(dv * Adn[1]);
    const float a2 = __expf(dv * Adn[2]);
    const float a3 = __expf(dv * Adn[3]);
    h0 = fmaf(a0, h0, dvx * B4.x);  p0 *= a0;
    h1 = fmaf(a1, h1, dvx * B4.y);  p1 *= a1;
    h2 = fmaf(a2, h2, dvx * B4.z);  p2 *= a2;
    h3 = fmaf(a3, h3, dvx * B4.w);  p3 *= a3;
  }

  const size_t base = (((size_t)(b * NCH + c) * DINNER) + d) * DSTATE + 4 * q;
  *reinterpret_cast<float4*>(hend  + base) = (float4){h0, h1, h2, h3};
  *reinterpret_cast<float4*>(aprod + base) = (float4){p0, p1, p2, p3};
}

__global__ __launch_bounds__(256)
void scan_combine(const float* __restrict__ hend, const float* __restrict__ aprod,
                  float* __restrict__ hin) {
  const int tid = blockIdx.x * 256 + threadIdx.x;   // 65536 total
  const size_t cstride = (size_t)DINNER * DSTATE;   // 32768
  const size_t base = (size_t)(tid >> 15) * NCH * cstride + (tid & 32767);
  float h = 0.f;
  hin[base] = 0.f;
  #pragma unroll
  for (int c = 0; c < NCH - 1; ++c) {
    h = fmaf(aprod[base + (size_t)c * cstride], h, hend[base + (size_t)c * cstride]);
    hin[base + (size_t)(c + 1) * cstride] = h;
  }
}

__global__ __launch_bounds__(64)
void scan_apply(const float* __restrict__ delta, const float* __restrict__ xc,
                const float* __restrict__ xdbl, const ushort* __restrict__ xzb,
                const float* __restrict__ A_log, const float* __restrict__ Dp,
                const float* __restrict__ hin, ushort* __restrict__ yh) {
  __shared__ float  dT[CL][16];
  __shared__ float  xT[CL][16];
  __shared__ float  bT[CL][16];
  __shared__ float  cT[CL][16];
  __shared__ ushort zT[CL][16];      // bf16 silu(z)

  const int idx = blockIdx.x;
  const int c  = idx & 15;
  const int dg = (idx >> 4) & 127;
  const int b  = idx >> 11;
  const int t  = threadIdx.x;
  const int ch = t >> 2;
  const int q  = t & 3;
  const int d  = dg * 16 + ch;

  const size_t r0 = (size_t)b * LL + (size_t)c * CL;
  stage_tile(delta + r0 * DINNER + dg * 16, DINNER, &dT[0][0], t);
  stage_tile(xc    + r0 * DINNER + dg * 16, DINNER, &xT[0][0], t);
  stage_tile(xdbl  + r0 * 96 + DTRANK,          96, &bT[0][0], t);
  stage_tile(xdbl  + r0 * 96 + DTRANK + DSTATE, 96, &cT[0][0], t);
  {
    // z tile: [64][16] bf16; 2 wave-wide 16B direct-to-LDS loads
    const ushort* g = xzb + (r0 << 12) + DINNER + dg * 16;
    const int r  = t >> 1;
    const int h8 = (t & 1) * 8;
    #pragma unroll
    for (int i = 0; i < 2; ++i) {
      __builtin_amdgcn_global_load_lds(
          AS1(g + (size_t)(i * 32 + r) * 4096 + h8),
          AS3(&zT[0][0] + i * 512), 16, 0, 0);
    }
  }

  float Adn[4];
  #pragma unroll
  for (int j = 0; j < 4; ++j)
    Adn[j] = -__expf(A_log[d * DSTATE + 4 * q + j]);
  const float Dd = Dp[d];

  const size_t base = (((size_t)(b * NCH + c) * DINNER) + d) * DSTATE + 4 * q;
  const float4 h4 = *reinterpret_cast<const float4*>(hin + base);
  float h0 = h4.x, h1 = h4.y, h2 = h4.z, h3 = h4.w;

  __syncthreads();

  #pragma unroll 8
  for (int l = 0; l < CL; ++l) {
    const float dv = dT[l][ch];
    const float xv = xT[l][ch];
    const float4 B4 = *reinterpret_cast<const float4*>(&bT[l][4 * q]);
    const float4 C4 = *reinterpret_cast<const float4*>(&cT[l][4 * q]);
    const float dvx = dv * xv;
    const float a0 = __expf(dv * Adn[0]);
    const float a1 = __expf(dv * Adn[1]);
    const float a2 = __expf(dv * Adn[2]);
    const float a3 = __expf(dv * Adn[3]);
    h0 = fmaf(a0, h0, dvx * B4.x);
    h1 = fmaf(a1, h1, dvx * B4.y);
    h2 = fmaf(a2, h2, dvx * B4.z);
    h3 = fmaf(a3, h3, dvx * B4.w);
    float ys = fmaf(h0, C4.x, fmaf(h1, C4.y, fmaf(h2, C4.z, h3 * C4.w)));
    ys = quad_sum(ys);
    if (q == 0) {
      const float g = bf2f(zT[l][ch]);   // silu(z), bf16 from in_proj epilogue
      const float tv = (ys + xv * Dd) * g;
      yh[(r0 + l) * (size_t)DINNER + d] = bf16_rne(tv);
    }
  }
}

// ---------------------------------------------------------------------------
extern "C" void kernel_launch(void* const* d_in, const int* in_sizes, int n_in,
                              void* d_out, int out_size, void* d_ws, size_t ws_size,
                              hipStream_t stream) {
  const float* x         = (const float*)d_in[0];
  const float* in_proj_w = (const float*)d_in[1];
  const float* conv_w    = (const float*)d_in[2];
  const float* conv_b    = (const float*)d_in[3];
  const float* x_proj_w  = (const float*)d_in[4];
  const float* dt_proj_w = (const float*)d_in[5];
  const float* dt_proj_b = (const float*)d_in[6];
  const float* A_log     = (const float*)d_in[7];
  const float* Dv        = (const float*)d_in[8];
  const float* out_proj_w= (const float*)d_in[9];
  float* out = (float*)d_out;

  float* ws    = (float*)d_ws;
  float* xz    = ws;                          // region reserved [2048][4096] f32;
                                              // used as bf16 [2048][4096] ushort
  float* xc    = xz    + (size_t)MM * 4096;   // [2048][2048] f32
  float* xdbl  = xc    + (size_t)MM * DINNER; // [2048][96]   f32
  float* delta = xdbl  + (size_t)MM * 96;     // [2048][2048] f32
  ushort* us   = (ushort*)(delta + (size_t)MM * DINNER);
  ushort* yhp  = us;                           // [2048][2048] bf16 hi
  ushort* ylp  = yhp + (size_t)MM * DINNER;    // repurposed: dt/wd planes
  ushort* xh   = ylp + (size_t)MM * DINNER;    // [2048][1024]
  ushort* xl   = xh  + (size_t)MM * DMODEL;    // (unused)
  ushort* wih  = xl  + (size_t)MM * DMODEL;    // [4096][1024]
  ushort* wil  = wih + (size_t)4096 * DMODEL;  // (unused)
  ushort* woh  = wil + (size_t)4096 * DMODEL;  // [1024][2048]

  ushort* xzb = (ushort*)xz;                   // bf16 view of xz

  // dt hi/lo + dt_proj_w hi/lo live in the old yl region
  ushort* dth = ylp;
  ushort* dtl = ylp + 131072;
  ushort* wdh = ylp + 262144;
  ushort* wdl = ylp + 393216;

  // hend/aprod/hin (scan) live in wih/wil (dead after in_proj GEMM)
  float* hend  = (float*)wih;
  float* aprod = hend  + (size_t)BB * NCH * DINNER * DSTATE;
  float* hin   = aprod + (size_t)BB * NCH * DINNER * DSTATE;
  // x_proj split-K partials [8][2048][96] = 6.3 MB (consumed before scan)
  float* part  = hend;
  // out_proj split-K partials [4][2048][1024] f32 = 33.55 MB = the reserved
  // xz region (dead after scan_apply reads the z half)
  float* opart = xz;

  const dim3 blk(256);

  // 0) fused precision splits (x hi, in_proj_w hi, out_proj_w hi, dt_proj_w hi+lo)
  {
    const int n0 = (MM * DMODEL) / 4, n1 = (4096 * DMODEL) / 4,
              n2 = (DMODEL * DINNER) / 4, n3 = (DINNER * DTRANK) / 4;
    split3<<<dim3((n0 + n1 + n2 + n3) / 256), blk, 0, stream>>>(
        x, xh, nullptr, n0, in_proj_w, wih, nullptr, n1,
        out_proj_w, woh, nullptr, n2, dt_proj_w, wdh, wdl, n3);
  }

  // 1) in_proj (1-product bf16 MFMA, coalesced bf16 epilogue + z-gate silu)
  gemm_p1_mfma<2, 1, true><<<dim3(4096 / 128, MM / 128), blk, 0, stream>>>(
      xh, wih, nullptr, xzb, MM, 4096, DMODEL);

  // 2) causal depthwise conv + silu -> xc (reads bf16 xz)
  conv_silu<<<dim3((MM * DINNER / 4) / 256), blk, 0, stream>>>(xzb, conv_w, conv_b, xc);

  // 3) x_proj split-K + fused reduce/dt-split
  gemm_nt_part<64,32,4,2,256><<<dim3(96/32, MM/64, 8), blk, 0, stream>>>(
      xc, x_proj_w, part, MM, 96, DINNER, DINNER);
  xpr_fused<<<dim3((MM * 24 + 255) / 256), blk, 0, stream>>>(part, xdbl, dth, dtl);

  // 4) dt_proj (MFMA split-bf16 3-product + softplus)
  gemm_hl_mfma<1,1><<<dim3(DINNER / 128, MM / 128), blk, 0, stream>>>(
      dth, dtl, wdh, wdl, delta, dt_proj_b, MM, DINNER, DTRANK);

  // 5) chunked parallel scan
  scan_chunk_state<<<dim3(BB * 128 * NCH), dim3(64), 0, stream>>>(
      delta, xc, xdbl, A_log, hend, aprod);
  scan_combine<<<dim3(BB * DINNER * DSTATE / 256), blk, 0, stream>>>(
      hend, aprod, hin);
  scan_apply<<<dim3(BB * 128 * NCH), dim3(64), 0, stream>>>(
      delta, xc, xdbl, xzb, A_log, Dv, hin, yhp);

  // 6) out_proj (1-product bf16 MFMA, coalesced f32 epilogue, split-K=4)
  gemm_p1_mfma<0, 4, false><<<dim3(DMODEL / 128, MM / 128, 4), blk, 0, stream>>>(
      yhp, woh, opart, nullptr, MM, DMODEL, DINNER);
  splitk_reduce4<<<dim3((MM * DMODEL) / 1024), blk, 0, stream>>>(
      opart, out, MM * DMODEL);
}

// Round 14
// 167.056 us; speedup vs baseline: 1.1890x; 1.0023x over previous
//
#include <hip/hip_runtime.h>
#include <math.h>
#include <stdint.h>

#define DMODEL 1024
#define DINNER 2048
#define DCONV  4
#define DSTATE 16
#define DTRANK 64
#define BB 2
#define LL 1024
#define MM (BB * LL)            // 2048 rows in all GEMMs

#define CL  64                  // scan chunk length
#define NCH (LL / CL)           // 16 chunks

#define AS1(p) ((__attribute__((address_space(1))) void*)(void*)(p))
#define AS3(p) ((__attribute__((address_space(3))) void*)(void*)(p))

typedef __attribute__((ext_vector_type(8))) short bf16x8;
typedef __attribute__((ext_vector_type(4))) float f32x4;

__device__ __forceinline__ ushort bf16_rne(float f) {
  uint32_t u = __float_as_uint(f);
  uint32_t r = (u + 0x7fffu + ((u >> 16) & 1u)) >> 16;
  return (ushort)r;
}
__device__ __forceinline__ float bf2f(ushort u) {
  return __uint_as_float((uint32_t)u << 16);
}

// ---------------------------------------------------------------------------
// Fused f32 -> (hi[, lo]) bf16 split for 4 arrays in one launch.
// ---------------------------------------------------------------------------
__device__ __forceinline__ void split4(const float* __restrict__ in,
                                       ushort* __restrict__ hi,
                                       ushort* __restrict__ lo, int i4) {
  const float4 v = *reinterpret_cast<const float4*>(in + (size_t)i4 * 4);
  ushort4 h;
  h.x = bf16_rne(v.x); h.y = bf16_rne(v.y);
  h.z = bf16_rne(v.z); h.w = bf16_rne(v.w);
  *reinterpret_cast<ushort4*>(hi + (size_t)i4 * 4) = h;
  if (lo) {
    ushort4 l;
    l.x = bf16_rne(v.x - bf2f(h.x));
    l.y = bf16_rne(v.y - bf2f(h.y));
    l.z = bf16_rne(v.z - bf2f(h.z));
    l.w = bf16_rne(v.w - bf2f(h.w));
    *reinterpret_cast<ushort4*>(lo + (size_t)i4 * 4) = l;
  }
}

__global__ __launch_bounds__(256)
void split3(const float* s0, ushort* h0, ushort* l0, int n0,
            const float* s1, ushort* h1, ushort* l1, int n1,
            const float* s2, ushort* h2, ushort* l2, int n2,
            const float* s3, ushort* h3, ushort* l3, int n3) {
  int i = blockIdx.x * 256 + threadIdx.x;
  if (i < n0) { split4(s0, h0, l0, i); return; }
  i -= n0;
  if (i < n1) { split4(s1, h1, l1, i); return; }
  i -= n1;
  if (i < n2) { split4(s2, h2, l2, i); return; }
  i -= n2;
  if (i < n3) { split4(s3, h3, l3, i); return; }
}

__device__ __forceinline__ int swz4(int r) { return (r & 3) ^ ((r >> 2) & 3); }

// ---------------------------------------------------------------------------
// 1-product MFMA NT GEMM with LDS-coalesced epilogue + XCD block swizzle.
// C = Ah @ Bh^T, 2 staged planes, 32 KB LDS, 2-phase double-buffered,
// SPLITK via blockIdx.z.
// EPI 0: plain f32.  EPI 1: softplus(acc+bias[n]) f32 (dt_proj).
// EPI 2: silu for column-blocks n0 >= DINNER, bf16 out (in_proj z-gate).
// OBF16: store bf16 (Pb); else f32 (Pf).
// ---------------------------------------------------------------------------
template<int EPI, int SPLITK, bool OBF16>
__global__ __launch_bounds__(256)
void gemm_p1_mfma(const ushort* __restrict__ Ahg, const ushort* __restrict__ Bhg,
                  float* __restrict__ Pf, ushort* __restrict__ Pb,
                  const float* __restrict__ bias, int M, int N, int K) {
  __shared__ ushort smem[16384];     // 32 KB: A planes [0,8192), B [8192,16384)

  // XCD-aware bijective block swizzle (nwg % 8 == 0 for all uses here)
  const int gx  = gridDim.x;
  const int nwg = gx * gridDim.y;
  const int orig = blockIdx.y * gx + blockIdx.x;
  const int cpx  = nwg >> 3;
  const int swzb = (orig & 7) * cpx + (orig >> 3);
  const int m0 = (swzb / gx) * 128;
  const int n0 = (swzb % gx) * 128;

  const int tid  = threadIdx.x;
  const int wave = tid >> 6;
  const int lane = tid & 63;
  const int wm = (wave >> 1) * 64;
  const int wn = (wave & 1) * 64;

  const int ksl = K / SPLITK;
  const int kb  = blockIdx.z * ksl;

  f32x4 acc[4][4];
  #pragma unroll
  for (int i = 0; i < 4; ++i)
    #pragma unroll
    for (int j = 0; j < 4; ++j)
      acc[i][j] = (f32x4){0.f, 0.f, 0.f, 0.f};

  const ushort* gsrc = nullptr; ushort* dst = nullptr; int row0 = 0;
  if      (wave == 0) { gsrc = Ahg; dst = smem;        row0 = m0; }
  else if (wave == 1) { gsrc = Bhg; dst = smem + 8192; row0 = n0; }

  const int lr = lane >> 2;
  const int ls = lane & 3;
  const int fr = lane & 15;
  const int q  = lane >> 4;

  auto STAGE = [&](int bi, int k0) {
    if (wave >= 2) return;
    ushort* d = dst + bi * 4096;
    #pragma unroll
    for (int seg = 0; seg < 8; ++seg) {
      const int rho = seg * 16 + lr;
      const int ks  = (ls ^ swz4(rho)) * 8;
      __builtin_amdgcn_global_load_lds(
          AS1(gsrc + (size_t)(row0 + rho) * K + k0 + ks),
          AS3(d + seg * 512), 16, 0, 0);
    }
  };

  const int NT = ksl / 32;
  STAGE(0, kb);
  __syncthreads();

  int cur = 0;
  for (int kt = 0; kt < NT; ++kt) {
    if (kt + 1 < NT) STAGE(cur ^ 1, kb + (kt + 1) * 32);

    bf16x8 ah[4], bh[4];
    #pragma unroll
    for (int f = 0; f < 4; ++f) {
      { const int r = wm + f * 16 + fr; const int s = 8 * (q ^ swz4(r));
        ah[f] = *reinterpret_cast<const bf16x8*>(&smem[cur * 4096 + r * 32 + s]); }
      { const int r = wn + f * 16 + fr; const int s = 8 * (q ^ swz4(r));
        bh[f] = *reinterpret_cast<const bf16x8*>(&smem[8192 + cur * 4096 + r * 32 + s]); }
    }
    #pragma unroll
    for (int i = 0; i < 4; ++i)
      #pragma unroll
      for (int j = 0; j < 4; ++j)
        acc[i][j] = __builtin_amdgcn_mfma_f32_16x16x32_bf16(ah[i], bh[j], acc[i][j], 0, 0, 0);

    __syncthreads();
    cur ^= 1;
  }
  // loop ends with a barrier -> LDS is free; each wave uses its own 8 KB slice.

  float* T = reinterpret_cast<float*>(smem) + wave * 2048;   // [32][64]
  const int cr = (lane >> 4) * 4;
  const int cc = lane & 15;
  const bool do_silu = (EPI == 2) && (n0 >= DINNER);

  #pragma unroll
  for (int p = 0; p < 2; ++p) {
    #pragma unroll
    for (int ii = 0; ii < 2; ++ii) {
      const int i = 2 * p + ii;
      #pragma unroll
      for (int j = 0; j < 4; ++j)
        #pragma unroll
        for (int r = 0; r < 4; ++r)
          T[(ii * 16 + cr + r) * 64 + j * 16 + cc] = acc[i][j][r];
    }
    #pragma unroll
    for (int rr = 0; rr < 8; ++rr) {
      const int row  = rr * 4 + (lane >> 4);     // 0..31
      const int col4 = (lane & 15) * 4;
      float4 v = *reinterpret_cast<const float4*>(&T[row * 64 + col4]);
      const size_t grow = (size_t)(m0 + wm + p * 32 + row);
      const int    gcol = n0 + wn + col4;
      if (EPI == 1) {
        v.x += bias[gcol + 0]; v.y += bias[gcol + 1];
        v.z += bias[gcol + 2]; v.w += bias[gcol + 3];
        v.x = fmaxf(v.x, 0.f) + __logf(1.f + __expf(-fabsf(v.x)));
        v.y = fmaxf(v.y, 0.f) + __logf(1.f + __expf(-fabsf(v.y)));
        v.z = fmaxf(v.z, 0.f) + __logf(1.f + __expf(-fabsf(v.z)));
        v.w = fmaxf(v.w, 0.f) + __logf(1.f + __expf(-fabsf(v.w)));
      }
      if (do_silu) {
        v.x = v.x / (1.f + __expf(-v.x));
        v.y = v.y / (1.f + __expf(-v.y));
        v.z = v.z / (1.f + __expf(-v.z));
        v.w = v.w / (1.f + __expf(-v.w));
      }
      if (OBF16) {
        ushort4 h;
        h.x = bf16_rne(v.x); h.y = bf16_rne(v.y);
        h.z = bf16_rne(v.z); h.w = bf16_rne(v.w);
        *reinterpret_cast<ushort4*>(Pb + grow * N + gcol) = h;
      } else {
        float* Cout = Pf + (size_t)blockIdx.z * M * N;
        *reinterpret_cast<float4*>(Cout + grow * N + gcol) = v;
      }
    }
  }
}

// sum 4 split-K partial planes -> out
__global__ __launch_bounds__(256)
void splitk_reduce4(const float* __restrict__ P, float* __restrict__ out, int n) {
  const int i = (blockIdx.x * 256 + threadIdx.x) * 4;
  if (i >= n) return;
  float4 s = *reinterpret_cast<const float4*>(P + i);
  #pragma unroll
  for (int z = 1; z < 4; ++z) {
    const float4 v = *reinterpret_cast<const float4*>(P + (size_t)z * n + i);
    s.x += v.x; s.y += v.y; s.z += v.z; s.w += v.w;
  }
  *reinterpret_cast<float4*>(out + i) = s;
}

// ---------------------------------------------------------------------------
// Split-K f32 NT GEMM partials (x_proj)
// ---------------------------------------------------------------------------
template<int BM, int BN, int TM, int TN, int KSLICE>
__global__ __launch_bounds__(256)
void gemm_nt_part(const float* __restrict__ A, const float* __restrict__ Bw,
                  float* __restrict__ P, int M, int N, int lda, int ldb) {
  constexpr int BK  = 16;
  constexpr int NTX = BN / TN;
  constexpr int NTY = BM / TM;
  static_assert(NTX * NTY == 256, "thread tile mismatch");
  __shared__ float As[BK][BM + 4];
  __shared__ float Bs[BK][BN + 4];

  const int tid = threadIdx.x;
  const int m0  = blockIdx.y * BM;
  const int n0  = blockIdx.x * BN;
  const int kb  = blockIdx.z * KSLICE;
  const int tx  = tid % NTX;
  const int ty  = tid / NTX;

  float acc[TM][TN] = {};

  for (int k0 = kb; k0 < kb + KSLICE; k0 += BK) {
    __syncthreads();
    for (int t = tid; t < BM * 4; t += 256) {
      const int row = t >> 2, kq = t & 3;
      const float4 v = *reinterpret_cast<const float4*>(
          A + (size_t)(m0 + row) * lda + k0 + kq * 4);
      As[kq * 4 + 0][row] = v.x;
      As[kq * 4 + 1][row] = v.y;
      As[kq * 4 + 2][row] = v.z;
      As[kq * 4 + 3][row] = v.w;
    }
    for (int t = tid; t < BN * 4; t += 256) {
      const int row = t >> 2, kq = t & 3;
      const float4 v = *reinterpret_cast<const float4*>(
          Bw + (size_t)(n0 + row) * ldb + k0 + kq * 4);
      Bs[kq * 4 + 0][row] = v.x;
      Bs[kq * 4 + 1][row] = v.y;
      Bs[kq * 4 + 2][row] = v.z;
      Bs[kq * 4 + 3][row] = v.w;
    }
    __syncthreads();
    #pragma unroll
    for (int k = 0; k < BK; ++k) {
      float a[TM], b[TN];
      #pragma unroll
      for (int i = 0; i < TM; ++i) a[i] = As[k][ty * TM + i];
      #pragma unroll
      for (int j = 0; j < TN; ++j) b[j] = Bs[k][tx * TN + j];
      #pragma unroll
      for (int i = 0; i < TM; ++i)
        #pragma unroll
        for (int j = 0; j < TN; ++j)
          acc[i][j] = fmaf(a[i], b[j], acc[i][j]);
    }
  }

  float* out = P + (size_t)blockIdx.z * M * N;
  #pragma unroll
  for (int i = 0; i < TM; ++i)
    #pragma unroll
    for (int j = 0; j < TN; ++j)
      out[(size_t)(m0 + ty * TM + i) * N + n0 + tx * TN + j] = acc[i][j];
}

// reduce x_proj partials; dt cols (0..63) -> packed bf16, B/C cols -> f32
__global__ __launch_bounds__(256)
void xpr_fused(const float* __restrict__ part, float* __restrict__ xdbl,
               ushort* __restrict__ dth) {
  const int i = blockIdx.x * 256 + threadIdx.x;   // float4 over [2048][24]
  if (i >= MM * 24) return;
  const int m  = i / 24;
  const int c4 = (i % 24) * 4;
  const size_t off = (size_t)m * 96 + c4;
  float4 s = *reinterpret_cast<const float4*>(part + off);
  #pragma unroll
  for (int z = 1; z < 8; ++z) {
    const float4 v = *reinterpret_cast<const float4*>(part + (size_t)z * MM * 96 + off);
    s.x += v.x; s.y += v.y; s.z += v.z; s.w += v.w;
  }
  if (c4 < 64) {
    ushort4 h;
    h.x = bf16_rne(s.x); h.y = bf16_rne(s.y);
    h.z = bf16_rne(s.z); h.w = bf16_rne(s.w);
    *reinterpret_cast<ushort4*>(dth + (size_t)m * 64 + c4) = h;
  } else {
    *reinterpret_cast<float4*>(xdbl + off) = s;
  }
}

// ---------------------------------------------------------------------------
// Depthwise causal conv1d (k=4) + bias + SiLU; reads bf16 xz, writes f32 xc.
// ---------------------------------------------------------------------------
__global__ __launch_bounds__(256)
void conv_silu(const ushort* __restrict__ xzb, const float* __restrict__ cw,
               const float* __restrict__ cb, float* __restrict__ xc) {
  const int idx = blockIdx.x * 256 + threadIdx.x;   // over MM*DINNER/4
  if (idx >= MM * DINNER / 4) return;
  const int d4 = (idx & 511) * 4;       // DINNER/4 = 512 per row
  const int m  = idx >> 9;
  const int l  = m & (LL - 1);
  const int b  = m >> 10;

  float4 w0 = *reinterpret_cast<const float4*>(cw + (size_t)(d4 + 0) * 4);
  float4 w1 = *reinterpret_cast<const float4*>(cw + (size_t)(d4 + 1) * 4);
  float4 w2 = *reinterpret_cast<const float4*>(cw + (size_t)(d4 + 2) * 4);
  float4 w3 = *reinterpret_cast<const float4*>(cw + (size_t)(d4 + 3) * 4);
  float4 acc = *reinterpret_cast<const float4*>(cb + d4);

  #pragma unroll
  for (int j = 0; j < DCONV; ++j) {
    const int ll = l - (DCONV - 1) + j;
    if (ll >= 0) {
      const ushort4 xv = *reinterpret_cast<const ushort4*>(
          xzb + ((size_t)(b * LL + ll) << 12) + d4);
      acc.x = fmaf(bf2f(xv.x), (&w0.x)[j], acc.x);
      acc.y = fmaf(bf2f(xv.y), (&w1.x)[j], acc.y);
      acc.z = fmaf(bf2f(xv.z), (&w2.x)[j], acc.z);
      acc.w = fmaf(bf2f(xv.w), (&w3.x)[j], acc.w);
    }
  }
  float4 o;
  o.x = acc.x / (1.f + __expf(-acc.x));
  o.y = acc.y / (1.f + __expf(-acc.y));
  o.z = acc.z / (1.f + __expf(-acc.z));
  o.w = acc.w / (1.f + __expf(-acc.w));
  *reinterpret_cast<float4*>(xc + (size_t)m * DINNER + d4) = o;
}

// ---------------------------------------------------------------------------
// Chunked parallel selective scan (3 passes).
// ---------------------------------------------------------------------------
__device__ __forceinline__ void stage_tile(const float* g, int stride,
                                           float* ldst, int lane) {
  const int r  = lane >> 2;
  const int q4 = (lane & 3) * 4;
  #pragma unroll
  for (int i = 0; i < 4; ++i) {
    __builtin_amdgcn_global_load_lds(
        AS1(g + (size_t)(i * 16 + r) * stride + q4),
        AS3(ldst + i * 256), 16, 0, 0);
  }
}

__device__ __forceinline__ float quad_sum(float v) {
  int i = __float_as_int(v);
  v += __int_as_float(__builtin_amdgcn_update_dpp(0, i, 0xB1, 0xf, 0xf, true)); // xor 1
  i = __float_as_int(v);
  v += __int_as_float(__builtin_amdgcn_update_dpp(0, i, 0x4E, 0xf, 0xf, true)); // xor 2
  return v;
}

__global__ __launch_bounds__(64)
void scan_chunk_state(const float* __restrict__ delta, const float* __restrict__ xc,
                      const float* __restrict__ xdbl, const float* __restrict__ A_log,
                      float* __restrict__ hend, float* __restrict__ aprod) {
  __shared__ float dT[CL][16];
  __shared__ float xT[CL][16];
  __shared__ float bT[CL][16];

  const int idx = blockIdx.x;          // (b*128 + dg)*16 + c
  const int c  = idx & 15;
  const int dg = (idx >> 4) & 127;
  const int b  = idx >> 11;
  const int t  = threadIdx.x;
  const int ch = t >> 2;
  const int q  = t & 3;
  const int d  = dg * 16 + ch;

  const size_t r0 = (size_t)b * LL + (size_t)c * CL;
  stage_tile(delta + r0 * DINNER + dg * 16, DINNER, &dT[0][0], t);
  stage_tile(xc    + r0 * DINNER + dg * 16, DINNER, &xT[0][0], t);
  stage_tile(xdbl  + r0 * 96 + DTRANK,          96, &bT[0][0], t);

  float Adn[4];
  #pragma unroll
  for (int j = 0; j < 4; ++j)
    Adn[j] = -__expf(A_log[d * DSTATE + 4 * q + j]);
  float h0 = 0.f, h1 = 0.f, h2 = 0.f, h3 = 0.f;
  float p0 = 1.f, p1 = 1.f, p2 = 1.f, p3 = 1.f;

  __syncthreads();

  #pragma unroll 8
  for (int l = 0; l < CL; ++l) {
    const float dv = dT[l][ch];
    const float xv = xT[l][ch];
    const float4 B4 = *reinterpret_cast<const float4*>(&bT[l][4 * q]);
    const float dvx = dv * xv;
    const float a0 = __expf(dv * Adn[0]);
    const float a1 = __expf(dv * Adn[1]);
    const float a2 = __expf(dv * Adn[2]);
    const float a3 = __expf(dv * Adn[3]);
    h0 = fmaf(a0, h0, dvx * B4.x);  p0 *= a0;
    h1 = fmaf(a1, h1, dvx * B4.y);  p1 *= a1;
    h2 = fmaf(a2, h2, dvx * B4.z);  p2 *= a2;
    h3 = fmaf(a3, h3, dvx * B4.w);  p3 *= a3;
  }

  const size_t base = (((size_t)(b * NCH + c) * DINNER) + d) * DSTATE + 4 * q;
  *reinterpret_cast<float4*>(hend  + base) = (float4){h0, h1, h2, h3};
  *reinterpret_cast<float4*>(aprod + base) = (float4){p0, p1, p2, p3};
}

__global__ __launch_bounds__(256)
void scan_combine(const float* __restrict__ hend, const float* __restrict__ aprod,
                  float* __restrict__ hin) {
  const int tid = blockIdx.x * 256 + threadIdx.x;   // 65536 total
  const size_t cstride = (size_t)DINNER * DSTATE;   // 32768
  const size_t base = (size_t)(tid >> 15) * NCH * cstride + (tid & 32767);
  float h = 0.f;
  hin[base] = 0.f;
  #pragma unroll
  for (int c = 0; c < NCH - 1; ++c) {
    h = fmaf(aprod[base + (size_t)c * cstride], h, hend[base + (size_t)c * cstride]);
    hin[base + (size_t)(c + 1) * cstride] = h;
  }
}

__global__ __launch_bounds__(64)
void scan_apply(const float* __restrict__ delta, const float* __restrict__ xc,
                const float* __restrict__ xdbl, const ushort* __restrict__ xzb,
                const float* __restrict__ A_log, const float* __restrict__ Dp,
                const float* __restrict__ hin, ushort* __restrict__ yh) {
  __shared__ float  dT[CL][16];
  __shared__ float  xT[CL][16];
  __shared__ float  bT[CL][16];
  __shared__ float  cT[CL][16];
  __shared__ ushort zT[CL][16];      // bf16 silu(z)

  const int idx = blockIdx.x;
  const int c  = idx & 15;
  const int dg = (idx >> 4) & 127;
  const int b  = idx >> 11;
  const int t  = threadIdx.x;
  const int ch = t >> 2;
  const int q  = t & 3;
  const int d  = dg * 16 + ch;

  const size_t r0 = (size_t)b * LL + (size_t)c * CL;
  stage_tile(delta + r0 * DINNER + dg * 16, DINNER, &dT[0][0], t);
  stage_tile(xc    + r0 * DINNER + dg * 16, DINNER, &xT[0][0], t);
  stage_tile(xdbl  + r0 * 96 + DTRANK,          96, &bT[0][0], t);
  stage_tile(xdbl  + r0 * 96 + DTRANK + DSTATE, 96, &cT[0][0], t);
  {
    const ushort* g = xzb + (r0 << 12) + DINNER + dg * 16;
    const int r  = t >> 1;
    const int h8 = (t & 1) * 8;
    #pragma unroll
    for (int i = 0; i < 2; ++i) {
      __builtin_amdgcn_global_load_lds(
          AS1(g + (size_t)(i * 32 + r) * 4096 + h8),
          AS3(&zT[0][0] + i * 512), 16, 0, 0);
    }
  }

  float Adn[4];
  #pragma unroll
  for (int j = 0; j < 4; ++j)
    Adn[j] = -__expf(A_log[d * DSTATE + 4 * q + j]);
  const float Dd = Dp[d];

  const size_t base = (((size_t)(b * NCH + c) * DINNER) + d) * DSTATE + 4 * q;
  const float4 h4 = *reinterpret_cast<const float4*>(hin + base);
  float h0 = h4.x, h1 = h4.y, h2 = h4.z, h3 = h4.w;

  __syncthreads();

  #pragma unroll 8
  for (int l = 0; l < CL; ++l) {
    const float dv = dT[l][ch];
    const float xv = xT[l][ch];
    const float4 B4 = *reinterpret_cast<const float4*>(&bT[l][4 * q]);
    const float4 C4 = *reinterpret_cast<const float4*>(&cT[l][4 * q]);
    const float dvx = dv * xv;
    const float a0 = __expf(dv * Adn[0]);
    const float a1 = __expf(dv * Adn[1]);
    const float a2 = __expf(dv * Adn[2]);
    const float a3 = __expf(dv * Adn[3]);
    h0 = fmaf(a0, h0, dvx * B4.x);
    h1 = fmaf(a1, h1, dvx * B4.y);
    h2 = fmaf(a2, h2, dvx * B4.z);
    h3 = fmaf(a3, h3, dvx * B4.w);
    float ys = fmaf(h0, C4.x, fmaf(h1, C4.y, fmaf(h2, C4.z, h3 * C4.w)));
    ys = quad_sum(ys);
    if (q == 0) {
      const float g = bf2f(zT[l][ch]);   // silu(z), bf16 from in_proj epilogue
      const float tv = (ys + xv * Dd) * g;
      yh[(r0 + l) * (size_t)DINNER + d] = bf16_rne(tv);
    }
  }
}

// ---------------------------------------------------------------------------
extern "C" void kernel_launch(void* const* d_in, const int* in_sizes, int n_in,
                              void* d_out, int out_size, void* d_ws, size_t ws_size,
                              hipStream_t stream) {
  const float* x         = (const float*)d_in[0];
  const float* in_proj_w = (const float*)d_in[1];
  const float* conv_w    = (const float*)d_in[2];
  const float* conv_b    = (const float*)d_in[3];
  const float* x_proj_w  = (const float*)d_in[4];
  const float* dt_proj_w = (const float*)d_in[5];
  const float* dt_proj_b = (const float*)d_in[6];
  const float* A_log     = (const float*)d_in[7];
  const float* Dv        = (const float*)d_in[8];
  const float* out_proj_w= (const float*)d_in[9];
  float* out = (float*)d_out;

  float* ws    = (float*)d_ws;
  float* xz    = ws;                          // reserved [2048][4096] f32;
                                              // used as bf16 [2048][4096]
  float* xc    = xz    + (size_t)MM * 4096;   // [2048][2048] f32
  float* xdbl  = xc    + (size_t)MM * DINNER; // [2048][96]   f32
  float* delta = xdbl  + (size_t)MM * 96;     // [2048][2048] f32
  ushort* us   = (ushort*)(delta + (size_t)MM * DINNER);
  ushort* yhp  = us;                           // [2048][2048] bf16 hi
  ushort* ylp  = yhp + (size_t)MM * DINNER;    // repurposed: dt/wd planes
  ushort* xh   = ylp + (size_t)MM * DINNER;    // [2048][1024]
  ushort* xl   = xh  + (size_t)MM * DMODEL;    // (unused)
  ushort* wih  = xl  + (size_t)MM * DMODEL;    // [4096][1024]
  ushort* wil  = wih + (size_t)4096 * DMODEL;  // (unused)
  ushort* woh  = wil + (size_t)4096 * DMODEL;  // [1024][2048]

  ushort* xzb = (ushort*)xz;                   // bf16 view of xz

  // dt + dt_proj_w bf16 planes live in the old yl region
  ushort* dth = ylp;
  ushort* wdh = ylp + 262144;

  // hend/aprod/hin (scan) live in wih/wil (dead after in_proj GEMM)
  float* hend  = (float*)wih;
  float* aprod = hend  + (size_t)BB * NCH * DINNER * DSTATE;
  float* hin   = aprod + (size_t)BB * NCH * DINNER * DSTATE;
  // x_proj split-K partials [8][2048][96] = 6.3 MB (consumed before scan)
  float* part  = hend;
  // out_proj split-K partials [4][2048][1024] f32 = the reserved xz region
  float* opart = xz;

  const dim3 blk(256);

  // 0) fused precision splits (x hi, in_proj_w hi, out_proj_w hi, dt_proj_w hi)
  {
    const int n0 = (MM * DMODEL) / 4, n1 = (4096 * DMODEL) / 4,
              n2 = (DMODEL * DINNER) / 4, n3 = (DINNER * DTRANK) / 4;
    split3<<<dim3((n0 + n1 + n2 + n3) / 256), blk, 0, stream>>>(
        x, xh, nullptr, n0, in_proj_w, wih, nullptr, n1,
        out_proj_w, woh, nullptr, n2, dt_proj_w, wdh, nullptr, n3);
  }

  // 1) in_proj (1-product bf16 MFMA, coalesced bf16 epilogue + z-gate silu)
  gemm_p1_mfma<2, 1, true><<<dim3(4096 / 128, MM / 128), blk, 0, stream>>>(
      xh, wih, nullptr, xzb, nullptr, MM, 4096, DMODEL);

  // 2) causal depthwise conv + silu -> xc (reads bf16 xz)
  conv_silu<<<dim3((MM * DINNER / 4) / 256), blk, 0, stream>>>(xzb, conv_w, conv_b, xc);

  // 3) x_proj split-K + fused reduce/dt-split
  gemm_nt_part<64,32,4,2,256><<<dim3(96/32, MM/64, 8), blk, 0, stream>>>(
      xc, x_proj_w, part, MM, 96, DINNER, DINNER);
  xpr_fused<<<dim3((MM * 24 + 255) / 256), blk, 0, stream>>>(part, xdbl, dth);

  // 4) dt_proj (1-product bf16 MFMA + softplus epilogue)
  gemm_p1_mfma<1, 1, false><<<dim3(DINNER / 128, MM / 128), blk, 0, stream>>>(
      dth, wdh, delta, nullptr, dt_proj_b, MM, DINNER, DTRANK);

  // 5) chunked parallel scan
  scan_chunk_state<<<dim3(BB * 128 * NCH), dim3(64), 0, stream>>>(
      delta, xc, xdbl, A_log, hend, aprod);
  scan_combine<<<dim3(BB * DINNER * DSTATE / 256), blk, 0, stream>>>(
      hend, aprod, hin);
  scan_apply<<<dim3(BB * 128 * NCH), dim3(64), 0, stream>>>(
      delta, xc, xdbl, xzb, A_log, Dv, hin, yhp);

  // 6) out_proj (1-product bf16 MFMA, coalesced f32 epilogue, split-K=4)
  gemm_p1_mfma<0, 4, false><<<dim3(DMODEL / 128, MM / 128, 4), blk, 0, stream>>>(
      yhp, woh, opart, nullptr, nullptr, MM, DMODEL, DINNER);
  splitk_reduce4<<<dim3((MM * DMODEL) / 1024), blk, 0, stream>>>(
      opart, out, MM * DMODEL);
}